// Round 5
// baseline (4153.538 us; speedup 1.0000x reference)
//
#include <hip/hip_runtime.h>
#include <math.h>

#define HDIM 128
typedef unsigned short u16;
typedef __attribute__((ext_vector_type(8))) short bf16x8;
typedef __attribute__((ext_vector_type(4))) float f32x4;

__device__ __forceinline__ u16 f2bf(float x) {
    unsigned u = __float_as_uint(x);
    u = (u + 0x7FFFu + ((u >> 16) & 1u)) >> 16;
    return (u16)u;
}
__device__ __forceinline__ float bf2f(u16 h) {
    return __uint_as_float(((unsigned)h) << 16);
}
__device__ __forceinline__ bf16x8 ld8(const u16* p) {
    return *reinterpret_cast<const bf16x8*>(p);
}
// split 8 fp32 -> bf16 hi (round-nearest) + bf16 lo (truncated remainder)
__device__ __forceinline__ void split8(const float* v, bf16x8& hi, bf16x8& lo) {
#pragma unroll
    for (int j = 0; j < 8; ++j) {
        unsigned u = __float_as_uint(v[j]);
        unsigned h = (u + 0x7FFFu + ((u >> 16) & 1u)) >> 16;
        float rem = v[j] - __uint_as_float(h << 16);
        hi[j] = (short)h;
        lo[j] = (short)(__float_as_uint(rem) >> 16);
    }
}
#define MFMA(acc, a, b) acc = __builtin_amdgcn_mfma_f32_16x16x32_bf16(a, b, acc, 0, 0, 0)

// ---------------- weight prep -----------------------------------------------
// Wfull[s][c2][r] = dot(Ws[s][r][:], Wih[c2][:])  (gi = (hagg@Ws)@Wih^T), hi/lo
__global__ __launch_bounds__(256) void prep_wfull(const float* __restrict__ Ws,
                                                  const float* __restrict__ Wih,
                                                  u16* __restrict__ hi, u16* __restrict__ lo) {
    int s = blockIdx.y;
    int idx = blockIdx.x * 256 + threadIdx.x;   // [0, 49152)
    int c2 = idx >> 7, r = idx & 127;
    const float* wr = Ws + (size_t)s * 16384 + (size_t)r * 128;
    const float* wc = Wih + (size_t)c2 * 128;
    float acc = 0.f;
#pragma unroll 8
    for (int k = 0; k < 128; k += 4) {
        float4 a = *reinterpret_cast<const float4*>(wr + k);
        float4 b = *reinterpret_cast<const float4*>(wc + k);
        acc += a.x * b.x + a.y * b.y + a.z * b.z + a.w * b.w;
    }
    size_t o = (size_t)s * 49152 + idx;
    u16 h = f2bf(acc);
    hi[o] = h; lo[o] = f2bf(acc - bf2f(h));
}

// straight split (Whh is already B^T = [384][128] row-major)
__global__ __launch_bounds__(256) void prep_split(const float* __restrict__ W,
                                                  u16* __restrict__ hi, u16* __restrict__ lo, int n) {
    int i = blockIdx.x * 256 + threadIdx.x;
    if (i < n) { float v = W[i]; u16 h = f2bf(v); hi[i] = h; lo[i] = f2bf(v - bf2f(h)); }
}

// WinT[r][c] = W_in[c][r], [128][64]
__global__ __launch_bounds__(256) void prep_win(const float* __restrict__ W,
                                                u16* __restrict__ hi, u16* __restrict__ lo) {
    int idx = blockIdx.x * 256 + threadIdx.x;        // 0..8191
    int r = idx >> 6, c = idx & 63;
    float v = W[(size_t)c * 128 + r];
    u16 h = f2bf(v);
    hi[idx] = h; lo[idx] = f2bf(v - bf2f(h));
}

// split x -> padded bf16 hi/lo
__global__ __launch_bounds__(256) void split_x(const float* __restrict__ x,
                                               u16* __restrict__ hi, u16* __restrict__ lo,
                                               int n, int ntot) {
    int i = blockIdx.x * 256 + threadIdx.x;
    if (i >= ntot) return;
    float v = (i < n) ? x[i] : 0.f;
    u16 h = f2bf(v);
    hi[i] = h; lo[i] = f2bf(v - bf2f(h));
}

// ---------------- embed: Hf = tanh(X @ Win), K=64, fp32 out -----------------
__global__ __launch_bounds__(256) void embed_k(const u16* __restrict__ Xhi, const u16* __restrict__ Xlo,
                                               const u16* __restrict__ Bhi, const u16* __restrict__ Blo,
                                               float* __restrict__ Hf) {
    const int tid = threadIdx.x, wave = tid >> 6, lane = tid & 63;
    const int row0 = blockIdx.x * 32, cs = wave * 32;
    const int lr = lane & 15, lk = (lane >> 4) * 8;
    f32x4 acc[2][2];
#pragma unroll
    for (int i = 0; i < 2; ++i)
#pragma unroll
        for (int j = 0; j < 2; ++j) acc[i][j] = (f32x4)0.f;
#pragma unroll
    for (int kc = 0; kc < 2; ++kc) {
        const size_t ao = (size_t)(row0 + lr) * 64 + kc * 32 + lk;
        bf16x8 ah0 = ld8(Xhi + ao), ah1 = ld8(Xhi + ao + 16 * 64);
        bf16x8 al0 = ld8(Xlo + ao), al1 = ld8(Xlo + ao + 16 * 64);
#pragma unroll
        for (int cf = 0; cf < 2; ++cf) {
            const size_t bo = (size_t)(cs + cf * 16 + lr) * 64 + kc * 32 + lk;
            bf16x8 bh = ld8(Bhi + bo), bl = ld8(Blo + bo);
            MFMA(acc[0][cf], ah0, bh); MFMA(acc[0][cf], ah0, bl); MFMA(acc[0][cf], al0, bh);
            MFMA(acc[1][cf], ah1, bh); MFMA(acc[1][cf], ah1, bl); MFMA(acc[1][cf], al1, bh);
        }
    }
#pragma unroll
    for (int rf = 0; rf < 2; ++rf)
#pragma unroll
        for (int cf = 0; cf < 2; ++cf)
#pragma unroll
            for (int rg = 0; rg < 4; ++rg) {
                int row = row0 + rf * 16 + (lane >> 4) * 4 + rg;
                int col = cs + cf * 16 + lr;
                Hf[(size_t)row * HDIM + col] = tanhf(acc[rf][cf][rg]);
            }
}

// ---------------- fused step: balanced gather -> LDS, split, GRU GEMM -------
// 512 threads = 8 waves; block covers 32 node-rows.
__global__ __launch_bounds__(512, 4) void step_k(const float* __restrict__ Hf,
                                                 const int* __restrict__ row_off,
                                                 const int2* __restrict__ sedge,
                                                 const u16* __restrict__ Wfhi, const u16* __restrict__ Wflo,
                                                 const u16* __restrict__ Whhi, const u16* __restrict__ Whlo,
                                                 const float* __restrict__ bih, const float* __restrict__ bhh,
                                                 float* __restrict__ Hnf, int Nn) {
    __shared__ float ag[32][136];        // fp32 gather accum; later aliased as hhh/hhl
    __shared__ u16 agh[32][136];
    __shared__ u16 agl[32][136];
    u16* hb = reinterpret_cast<u16*>(&ag[0][0]);   // hhh [32][136], hhl at +4352
    const int tid = threadIdx.x, wave = tid >> 6, lane = tid & 63;
    const int row0 = blockIdx.x * 32;

    // zero accumulator (incl. padding)
    for (int i = tid; i < 32 * 136; i += 512) (&ag[0][0])[i] = 0.f;
    __syncthreads();

    // ---- phase 1: edge-cooperative gather, LDS fp32 atomics ----
    const int rowEnd = (row0 + 32 < Nn) ? row0 + 32 : Nn;
    const int eLo = row_off[row0];
    const int eHi = row_off[rowEnd];
    for (int s = eLo + wave * 4; s < eHi; s += 32) {
        if (s + 4 <= eHi) {
            int2 e0 = sedge[s], e1 = sedge[s + 1], e2 = sedge[s + 2], e3 = sedge[s + 3];
            float2 v0 = *reinterpret_cast<const float2*>(Hf + (size_t)e0.x * HDIM + lane * 2);
            float2 v1 = *reinterpret_cast<const float2*>(Hf + (size_t)e1.x * HDIM + lane * 2);
            float2 v2 = *reinterpret_cast<const float2*>(Hf + (size_t)e2.x * HDIM + lane * 2);
            float2 v3 = *reinterpret_cast<const float2*>(Hf + (size_t)e3.x * HDIM + lane * 2);
            atomicAdd(&ag[e0.y - row0][lane * 2], v0.x); atomicAdd(&ag[e0.y - row0][lane * 2 + 1], v0.y);
            atomicAdd(&ag[e1.y - row0][lane * 2], v1.x); atomicAdd(&ag[e1.y - row0][lane * 2 + 1], v1.y);
            atomicAdd(&ag[e2.y - row0][lane * 2], v2.x); atomicAdd(&ag[e2.y - row0][lane * 2 + 1], v2.y);
            atomicAdd(&ag[e3.y - row0][lane * 2], v3.x); atomicAdd(&ag[e3.y - row0][lane * 2 + 1], v3.y);
        } else {
            for (int q = s; q < eHi; ++q) {
                int2 e = sedge[q];
                float2 v = *reinterpret_cast<const float2*>(Hf + (size_t)e.x * HDIM + lane * 2);
                atomicAdd(&ag[e.y - row0][lane * 2], v.x); atomicAdd(&ag[e.y - row0][lane * 2 + 1], v.y);
            }
        }
    }
    __syncthreads();

    // ---- phase 1b: split agg fp32 -> bf16 hi/lo (once per block) ----
    {
        const int r = tid >> 4, c0 = (tid & 15) * 8;
        float v[8];
        *reinterpret_cast<float4*>(&v[0]) = *reinterpret_cast<const float4*>(&ag[r][c0]);
        *reinterpret_cast<float4*>(&v[4]) = *reinterpret_cast<const float4*>(&ag[r][c0 + 4]);
        bf16x8 hi, lo;
        split8(v, hi, lo);
        *reinterpret_cast<bf16x8*>(&agh[r][c0]) = hi;
        *reinterpret_cast<bf16x8*>(&agl[r][c0]) = lo;
    }
    __syncthreads();

    // ---- phase 1c: load h rows, split -> LDS (aliases ag) ----
    {
        const int r = tid >> 4, c0 = (tid & 15) * 8;
        float v[8];
        const float* hp = Hf + (size_t)(row0 + r) * HDIM + c0;
        *reinterpret_cast<float4*>(&v[0]) = *reinterpret_cast<const float4*>(hp);
        *reinterpret_cast<float4*>(&v[4]) = *reinterpret_cast<const float4*>(hp + 4);
        bf16x8 hi, lo;
        split8(v, hi, lo);
        *reinterpret_cast<bf16x8*>(hb + r * 136 + c0) = hi;
        *reinterpret_cast<bf16x8*>(hb + 4352 + r * 136 + c0) = lo;
    }
    __syncthreads();

    // ---- phase 2: GEMM + gates; wave owns 16 cols (cs), 32 rows ----
    const int lr = lane & 15, lk = (lane >> 4) * 8, cs = wave * 16;
    f32x4 accI[2][3], accH[2][3];
#pragma unroll
    for (int rf = 0; rf < 2; ++rf)
#pragma unroll
        for (int g = 0; g < 3; ++g) { accI[rf][g] = (f32x4)0.f; accH[rf][g] = (f32x4)0.f; }
#pragma unroll
    for (int kc = 0; kc < 4; ++kc) {
        bf16x8 ga[2], gl[2], ha[2], hl[2];
#pragma unroll
        for (int rf = 0; rf < 2; ++rf) {
            const int rr = rf * 16 + lr, cc = kc * 32 + lk;
            ga[rf] = *reinterpret_cast<const bf16x8*>(&agh[rr][cc]);
            gl[rf] = *reinterpret_cast<const bf16x8*>(&agl[rr][cc]);
            ha[rf] = *reinterpret_cast<const bf16x8*>(hb + rr * 136 + cc);
            hl[rf] = *reinterpret_cast<const bf16x8*>(hb + 4352 + rr * 136 + cc);
        }
#pragma unroll
        for (int g = 0; g < 3; ++g) {
            const size_t bo = (size_t)(g * 128 + cs + lr) * HDIM + kc * 32 + lk;
            bf16x8 fh = ld8(Wfhi + bo), fl = ld8(Wflo + bo);
            bf16x8 wh = ld8(Whhi + bo), wl = ld8(Whlo + bo);
#pragma unroll
            for (int rf = 0; rf < 2; ++rf) {
                MFMA(accI[rf][g], ga[rf], fh); MFMA(accI[rf][g], ga[rf], fl); MFMA(accI[rf][g], gl[rf], fh);
                MFMA(accH[rf][g], ha[rf], wh); MFMA(accH[rf][g], ha[rf], wl); MFMA(accH[rf][g], hl[rf], wh);
            }
        }
    }
    const int c = cs + lr;
    const float bir = bih[c], biz = bih[128 + c], bin = bih[256 + c];
    const float bhr = bhh[c], bhz = bhh[128 + c], bhn = bhh[256 + c];
#pragma unroll
    for (int rf = 0; rf < 2; ++rf)
#pragma unroll
        for (int rg = 0; rg < 4; ++rg) {
            const int row = row0 + rf * 16 + (lane >> 4) * 4 + rg;
            float gir = accI[rf][0][rg] + bir;
            float giz = accI[rf][1][rg] + biz;
            float gin = accI[rf][2][rg] + bin;
            float ghr = accH[rf][0][rg] + bhr;
            float ghz = accH[rf][1][rg] + bhz;
            float ghn = accH[rf][2][rg] + bhn;
            float r = 1.f / (1.f + expf(-(gir + ghr)));
            float z = 1.f / (1.f + expf(-(giz + ghz)));
            float nn = tanhf(gin + r * ghn);
            size_t o = (size_t)row * HDIM + c;
            float hold = Hf[o];
            Hnf[o] = (1.f - z) * nn + z * hold;
        }
}

// ---------------- CSR build -------------------------------------------------
__global__ void zero_int(int* p, int n) {
    int i = blockIdx.x * 256 + threadIdx.x;
    if (i < n) p[i] = 0;
}

__global__ void hist_kernel(const int* __restrict__ dst, int* __restrict__ cnt, int E) {
    int e = blockIdx.x * 256 + threadIdx.x;
    if (e < E) atomicAdd(&cnt[dst[e]], 1);
}

// single-block chunked exclusive scan with wave shuffles
__global__ __launch_bounds__(1024) void scan_kernel(int* __restrict__ cnt_cursor,
                                                    int* __restrict__ row_off, int n) {
    __shared__ int wsum[16];
    __shared__ int carry_s;
    const int tid = threadIdx.x, lane = tid & 63, wv = tid >> 6;
    if (tid == 0) carry_s = 0;
    __syncthreads();
    for (int base = 0; base < n; base += 1024) {
        int i = base + tid;
        int v = (i < n) ? cnt_cursor[i] : 0;
        int x = v;
#pragma unroll
        for (int off = 1; off < 64; off <<= 1) {
            int t = __shfl_up(x, off);
            if (lane >= off) x += t;
        }
        if (lane == 63) wsum[wv] = x;
        __syncthreads();
        if (wv == 0 && lane < 16) {
            int s = wsum[lane];
#pragma unroll
            for (int off = 1; off < 16; off <<= 1) {
                int t = __shfl_up(s, off);
                if (lane >= off) s += t;
            }
            wsum[lane] = s;
        }
        __syncthreads();
        int wbase = (wv == 0) ? 0 : wsum[wv - 1];
        int carry = carry_s;
        int total = wsum[15];
        int excl = carry + wbase + x - v;
        if (i < n) { row_off[i] = excl; cnt_cursor[i] = excl; }
        __syncthreads();
        if (tid == 0) carry_s = carry + total;
        __syncthreads();
    }
    if (tid == 0) row_off[n] = carry_s;
}

__global__ void scatter_kernel(const int* __restrict__ src, const int* __restrict__ dst,
                               int* __restrict__ cursor, int2* __restrict__ sedge, int E) {
    int e = blockIdx.x * 256 + threadIdx.x;
    if (e < E) {
        int d = dst[e];
        int p = atomicAdd(&cursor[d], 1);
        sedge[p] = make_int2(src[e], d);
    }
}

// ---------------- mean-pool + relu ------------------------------------------
__global__ __launch_bounds__(256) void pool_k(const float* __restrict__ Hf,
                                              const int* __restrict__ batch,
                                              float* __restrict__ pooled, int M) {
    __shared__ int lo_s, hi_s;
    __shared__ float smx[256], smy[256];
    int g = blockIdx.x;
    if (threadIdx.x == 0) {
        int lo = 0, hi = M;
        while (lo < hi) { int mid = (lo + hi) >> 1; if (batch[mid] < g) lo = mid + 1; else hi = mid; }
        lo_s = lo;
        int lo2 = lo, hi2 = M;
        while (lo2 < hi2) { int mid = (lo2 + hi2) >> 1; if (batch[mid] < g + 1) lo2 = mid + 1; else hi2 = mid; }
        hi_s = lo2;
    }
    __syncthreads();
    int lo = lo_s, hi = hi_s;
    int c2 = threadIdx.x & 63, quarter = threadIdx.x >> 6;
    float ax = 0.f, ay = 0.f;
    for (int i = lo + quarter; i < hi; i += 4) {
        float2 v = *reinterpret_cast<const float2*>(Hf + (size_t)i * HDIM + c2 * 2);
        ax += v.x; ay += v.y;
    }
    smx[threadIdx.x] = ax; smy[threadIdx.x] = ay;
    __syncthreads();
    if (quarter == 0) {
        float sx = smx[c2] + smx[c2 + 64] + smx[c2 + 128] + smx[c2 + 192];
        float sy = smy[c2] + smy[c2 + 64] + smy[c2 + 128] + smy[c2 + 192];
        float cnt = (float)(hi - lo); if (cnt < 1.f) cnt = 1.f;
        pooled[g * HDIM + c2 * 2]     = fmaxf(sx / cnt, 0.f);
        pooled[g * HDIM + c2 * 2 + 1] = fmaxf(sy / cnt, 0.f);
    }
}

// ---------------- prediction head -------------------------------------------
__global__ void pred_kernel(const float* __restrict__ pa, const float* __restrict__ pv,
                            const float* __restrict__ pW, const float* __restrict__ pb,
                            float* __restrict__ out) {
    int g = blockIdx.x, lane = threadIdx.x; // 64 threads
    float s = pa[g * HDIM + lane] * pW[lane]
            + pa[g * HDIM + 64 + lane] * pW[64 + lane]
            + pv[g * HDIM + lane] * pW[HDIM + lane]
            + pv[g * HDIM + 64 + lane] * pW[192 + lane];
    for (int off = 32; off; off >>= 1) s += __shfl_down(s, off);
    if (lane == 0) out[g] = s + pb[0];
}

extern "C" void kernel_launch(void* const* d_in, const int* in_sizes, int n_in,
                              void* d_out, int out_size, void* d_ws, size_t ws_size,
                              hipStream_t stream) {
    const float* atom_x   = (const float*)d_in[0];
    const float* voro_x   = (const float*)d_in[1];
    const int*   atom_ei  = (const int*)d_in[2];
    const int*   voro_ei  = (const int*)d_in[3];
    const int*   batch    = (const int*)d_in[4];
    const float* W_at_in  = (const float*)d_in[5];
    const float* W_vo_in  = (const float*)d_in[6];
    const float* atom_W   = (const float*)d_in[7];
    const float* voro_W   = (const float*)d_in[8];
    const float* atom_Wih = (const float*)d_in[9];
    const float* atom_Whh = (const float*)d_in[10];
    const float* atom_bih = (const float*)d_in[11];
    const float* atom_bhh = (const float*)d_in[12];
    const float* voro_Wih = (const float*)d_in[13];
    const float* voro_Whh = (const float*)d_in[14];
    const float* voro_bih = (const float*)d_in[15];
    const float* voro_bhh = (const float*)d_in[16];
    const float* pred_W   = (const float*)d_in[17];
    const float* pred_b   = (const float*)d_in[18];
    float* out = (float*)d_out;

    const int Nn = in_sizes[4];
    const int Ee = in_sizes[2] / 2;
    const int Gg = out_size;
    const int Npad = (Nn + 31) & ~31;

    char* base = (char*)d_ws;
    size_t off = 0;
    auto alloc = [&](size_t bytes) -> char* {
        char* p = base + off;
        off = (off + bytes + 255) & ~(size_t)255;
        return p;
    };

    float* Hf  = (float*)alloc((size_t)Npad * HDIM * 4);
    float* Hnf = (float*)alloc((size_t)Npad * HDIM * 4);
    // X hi/lo alias Hnf (X is dead once embed finishes; first step then writes Hnf)
    u16* Xhi = (u16*)Hnf;
    u16* Xlo = Xhi + (size_t)Npad * 64;
    u16 *WfHi[2], *WfLo[2], *WhHi[2], *WhLo[2], *WnHi[2], *WnLo[2];
    for (int t = 0; t < 2; ++t) {
        WfHi[t] = (u16*)alloc(4 * 49152 * 2); WfLo[t] = (u16*)alloc(4 * 49152 * 2);
        WhHi[t] = (u16*)alloc(384 * 128 * 2); WhLo[t] = (u16*)alloc(384 * 128 * 2);
        WnHi[t] = (u16*)alloc(128 * 64 * 2);  WnLo[t] = (u16*)alloc(128 * 64 * 2);
    }
    float* pooledA = (float*)alloc((size_t)Gg * HDIM * 4);
    float* pooledV = (float*)alloc((size_t)Gg * HDIM * 4);
    int*  row_off = (int*)alloc((size_t)(Nn + 1) * 4);
    int*  cursor  = (int*)alloc((size_t)Nn * 4);
    int2* sedge   = (int2*)alloc((size_t)Ee * 8);

    const float* xs[2]   = {atom_x, voro_x};
    const float* Win[2]  = {W_at_in, W_vo_in};
    const int*   ei[2]   = {atom_ei, voro_ei};
    const float* Wst[2]  = {atom_W, voro_W};
    const float* Wih[2]  = {atom_Wih, voro_Wih};
    const float* Whh[2]  = {atom_Whh, voro_Whh};
    const float* bihp[2] = {atom_bih, voro_bih};
    const float* bhhp[2] = {atom_bhh, voro_bhh};
    float* pool2[2]      = {pooledA, pooledV};

    // weight prep
    for (int t = 0; t < 2; ++t) {
        prep_wfull<<<dim3(192, 4), 256, 0, stream>>>(Wst[t], Wih[t], WfHi[t], WfLo[t]);
        prep_split<<<192, 256, 0, stream>>>(Whh[t], WhHi[t], WhLo[t], 384 * 128);
        prep_win<<<32, 256, 0, stream>>>(Win[t], WnHi[t], WnLo[t]);
    }

    const int eb  = (Ee + 255) / 256;
    const int nb  = (Nn + 255) / 256;
    const int gbs = Npad / 32;

    for (int t = 0; t < 2; ++t) {
        split_x<<<(Npad * 64 + 255) / 256, 256, 0, stream>>>(xs[t], Xhi, Xlo, Nn * 64, Npad * 64);
        embed_k<<<gbs, 256, 0, stream>>>(Xhi, Xlo, WnHi[t], WnLo[t], Hf);

        zero_int<<<nb, 256, 0, stream>>>(cursor, Nn);
        hist_kernel<<<eb, 256, 0, stream>>>(ei[t] + Ee, cursor, Ee);
        scan_kernel<<<1, 1024, 0, stream>>>(cursor, row_off, Nn);
        scatter_kernel<<<eb, 256, 0, stream>>>(ei[t], ei[t] + Ee, cursor, sedge, Ee);

        float *hA = Hf, *hB = Hnf;
        for (int s = 0; s < 4; ++s) {
            step_k<<<gbs, 512, 0, stream>>>(hA, row_off, sedge,
                                            WfHi[t] + (size_t)s * 49152, WfLo[t] + (size_t)s * 49152,
                                            WhHi[t], WhLo[t], bihp[t], bhhp[t], hB, Nn);
            float* tp = hA; hA = hB; hB = tp;
        }
        pool_k<<<Gg, 256, 0, stream>>>(hA, batch, pool2[t], Nn);
    }
    pred_kernel<<<Gg, 64, 0, stream>>>(pooledA, pooledV, pred_W, pred_b, out);
}

// Round 6
// 1505.715 us; speedup vs baseline: 2.7585x; 2.7585x over previous
//
#include <hip/hip_runtime.h>
#include <math.h>

#define HDIM 128
typedef unsigned short u16;
typedef __attribute__((ext_vector_type(8))) short bf16x8;
typedef __attribute__((ext_vector_type(4))) float f32x4;

__device__ __forceinline__ u16 f2bf(float x) {
    unsigned u = __float_as_uint(x);
    u = (u + 0x7FFFu + ((u >> 16) & 1u)) >> 16;
    return (u16)u;
}
__device__ __forceinline__ float bf2f(u16 h) {
    return __uint_as_float(((unsigned)h) << 16);
}
__device__ __forceinline__ bf16x8 ld8(const u16* p) {
    return *reinterpret_cast<const bf16x8*>(p);
}
// split 8 fp32 -> bf16 hi (round-nearest) + bf16 lo (truncated remainder)
__device__ __forceinline__ void split8(const float* v, bf16x8& hi, bf16x8& lo) {
#pragma unroll
    for (int j = 0; j < 8; ++j) {
        unsigned u = __float_as_uint(v[j]);
        unsigned h = (u + 0x7FFFu + ((u >> 16) & 1u)) >> 16;
        float rem = v[j] - __uint_as_float(h << 16);
        hi[j] = (short)h;
        lo[j] = (short)(__float_as_uint(rem) >> 16);
    }
}
#define MFMA(acc, a, b) acc = __builtin_amdgcn_mfma_f32_16x16x32_bf16(a, b, acc, 0, 0, 0)

// ---------------- weight prep -----------------------------------------------
// Wfull[s][c2][r] = dot(Ws[s][r][:], Wih[c2][:])  (gi = (hagg@Ws)@Wih^T), hi/lo
__global__ __launch_bounds__(256) void prep_wfull(const float* __restrict__ Ws,
                                                  const float* __restrict__ Wih,
                                                  u16* __restrict__ hi, u16* __restrict__ lo) {
    int s = blockIdx.y;
    int idx = blockIdx.x * 256 + threadIdx.x;   // [0, 49152)
    int c2 = idx >> 7, r = idx & 127;
    const float* wr = Ws + (size_t)s * 16384 + (size_t)r * 128;
    const float* wc = Wih + (size_t)c2 * 128;
    float acc = 0.f;
#pragma unroll 8
    for (int k = 0; k < 128; k += 4) {
        float4 a = *reinterpret_cast<const float4*>(wr + k);
        float4 b = *reinterpret_cast<const float4*>(wc + k);
        acc += a.x * b.x + a.y * b.y + a.z * b.z + a.w * b.w;
    }
    size_t o = (size_t)s * 49152 + idx;
    u16 h = f2bf(acc);
    hi[o] = h; lo[o] = f2bf(acc - bf2f(h));
}

// straight split (Whh is already B^T = [384][128] row-major)
__global__ __launch_bounds__(256) void prep_split(const float* __restrict__ W,
                                                  u16* __restrict__ hi, u16* __restrict__ lo, int n) {
    int i = blockIdx.x * 256 + threadIdx.x;
    if (i < n) { float v = W[i]; u16 h = f2bf(v); hi[i] = h; lo[i] = f2bf(v - bf2f(h)); }
}

// WinT[r][c] = W_in[c][r], [128][64]
__global__ __launch_bounds__(256) void prep_win(const float* __restrict__ W,
                                                u16* __restrict__ hi, u16* __restrict__ lo) {
    int idx = blockIdx.x * 256 + threadIdx.x;        // 0..8191
    int r = idx >> 6, c = idx & 63;
    float v = W[(size_t)c * 128 + r];
    u16 h = f2bf(v);
    hi[idx] = h; lo[idx] = f2bf(v - bf2f(h));
}

// split x -> padded bf16 hi/lo
__global__ __launch_bounds__(256) void split_x(const float* __restrict__ x,
                                               u16* __restrict__ hi, u16* __restrict__ lo,
                                               int n, int ntot) {
    int i = blockIdx.x * 256 + threadIdx.x;
    if (i >= ntot) return;
    float v = (i < n) ? x[i] : 0.f;
    u16 h = f2bf(v);
    hi[i] = h; lo[i] = f2bf(v - bf2f(h));
}

// ---------------- embed: Hf = tanh(X @ Win), K=64, fp32 out -----------------
__global__ __launch_bounds__(256) void embed_k(const u16* __restrict__ Xhi, const u16* __restrict__ Xlo,
                                               const u16* __restrict__ Bhi, const u16* __restrict__ Blo,
                                               float* __restrict__ Hf) {
    const int tid = threadIdx.x, wave = tid >> 6, lane = tid & 63;
    const int row0 = blockIdx.x * 32, cs = wave * 32;
    const int lr = lane & 15, lk = (lane >> 4) * 8;
    f32x4 acc[2][2];
#pragma unroll
    for (int i = 0; i < 2; ++i)
#pragma unroll
        for (int j = 0; j < 2; ++j) acc[i][j] = (f32x4)0.f;
#pragma unroll
    for (int kc = 0; kc < 2; ++kc) {
        const size_t ao = (size_t)(row0 + lr) * 64 + kc * 32 + lk;
        bf16x8 ah0 = ld8(Xhi + ao), ah1 = ld8(Xhi + ao + 16 * 64);
        bf16x8 al0 = ld8(Xlo + ao), al1 = ld8(Xlo + ao + 16 * 64);
#pragma unroll
        for (int cf = 0; cf < 2; ++cf) {
            const size_t bo = (size_t)(cs + cf * 16 + lr) * 64 + kc * 32 + lk;
            bf16x8 bh = ld8(Bhi + bo), bl = ld8(Blo + bo);
            MFMA(acc[0][cf], ah0, bh); MFMA(acc[0][cf], ah0, bl); MFMA(acc[0][cf], al0, bh);
            MFMA(acc[1][cf], ah1, bh); MFMA(acc[1][cf], ah1, bl); MFMA(acc[1][cf], al1, bh);
        }
    }
#pragma unroll
    for (int rf = 0; rf < 2; ++rf)
#pragma unroll
        for (int cf = 0; cf < 2; ++cf)
#pragma unroll
            for (int rg = 0; rg < 4; ++rg) {
                int row = row0 + rf * 16 + (lane >> 4) * 4 + rg;
                int col = cs + cf * 16 + lr;
                Hf[(size_t)row * HDIM + col] = tanhf(acc[rf][cf][rg]);
            }
}

// ---------------- fused step: wave-per-node gather, split -> LDS, GEMM ------
// 512 threads = 8 waves; block covers 32 node-rows.
// phase 1: wave w gathers nodes w*4..w*4+3 in fp32 regs (1 float2 load/edge).
// phase 2: wave w computes cols w*16..w*16+16 of all 6 gate strips via MFMA.
__global__ __launch_bounds__(512, 4) void step_k(const float* __restrict__ Hf,
                                                 const int* __restrict__ row_off,
                                                 const int* __restrict__ ssrc,
                                                 const u16* __restrict__ Wfhi, const u16* __restrict__ Wflo,
                                                 const u16* __restrict__ Whhi, const u16* __restrict__ Whlo,
                                                 const float* __restrict__ bih, const float* __restrict__ bhh,
                                                 float* __restrict__ Hnf, int Nn) {
    __shared__ u16 agh[32][136];
    __shared__ u16 agl[32][136];
    __shared__ u16 hhh[32][136];
    __shared__ u16 hhl[32][136];
    const int tid = threadIdx.x, wave = tid >> 6, lane = tid & 63;
    const int row0 = blockIdx.x * 32;

    // ---- phase 1: gather neighbor-sum of h (fp32, register accum) ----
#pragma unroll
    for (int q = 0; q < 4; ++q) {
        const int nl = wave * 4 + q;
        const int node = row0 + nl;
        float ax = 0.f, ay = 0.f;
        if (node < Nn) {
            int lo = row_off[node], hi = row_off[node + 1];
            int i = lo;
            for (; i + 8 <= hi; i += 8) {
                float2 v0 = *reinterpret_cast<const float2*>(Hf + (size_t)ssrc[i] * HDIM + lane * 2);
                float2 v1 = *reinterpret_cast<const float2*>(Hf + (size_t)ssrc[i + 1] * HDIM + lane * 2);
                float2 v2 = *reinterpret_cast<const float2*>(Hf + (size_t)ssrc[i + 2] * HDIM + lane * 2);
                float2 v3 = *reinterpret_cast<const float2*>(Hf + (size_t)ssrc[i + 3] * HDIM + lane * 2);
                float2 v4 = *reinterpret_cast<const float2*>(Hf + (size_t)ssrc[i + 4] * HDIM + lane * 2);
                float2 v5 = *reinterpret_cast<const float2*>(Hf + (size_t)ssrc[i + 5] * HDIM + lane * 2);
                float2 v6 = *reinterpret_cast<const float2*>(Hf + (size_t)ssrc[i + 6] * HDIM + lane * 2);
                float2 v7 = *reinterpret_cast<const float2*>(Hf + (size_t)ssrc[i + 7] * HDIM + lane * 2);
                ax += ((v0.x + v1.x) + (v2.x + v3.x)) + ((v4.x + v5.x) + (v6.x + v7.x));
                ay += ((v0.y + v1.y) + (v2.y + v3.y)) + ((v4.y + v5.y) + (v6.y + v7.y));
            }
            for (; i + 4 <= hi; i += 4) {
                float2 v0 = *reinterpret_cast<const float2*>(Hf + (size_t)ssrc[i] * HDIM + lane * 2);
                float2 v1 = *reinterpret_cast<const float2*>(Hf + (size_t)ssrc[i + 1] * HDIM + lane * 2);
                float2 v2 = *reinterpret_cast<const float2*>(Hf + (size_t)ssrc[i + 2] * HDIM + lane * 2);
                float2 v3 = *reinterpret_cast<const float2*>(Hf + (size_t)ssrc[i + 3] * HDIM + lane * 2);
                ax += (v0.x + v1.x) + (v2.x + v3.x);
                ay += (v0.y + v1.y) + (v2.y + v3.y);
            }
            for (; i < hi; ++i) {
                float2 v = *reinterpret_cast<const float2*>(Hf + (size_t)ssrc[i] * HDIM + lane * 2);
                ax += v.x; ay += v.y;
            }
        }
        u16 hx = f2bf(ax), hy = f2bf(ay);
        u16 lx = f2bf(ax - bf2f(hx)), ly = f2bf(ay - bf2f(hy));
        *reinterpret_cast<unsigned*>(&agh[nl][lane * 2]) = (unsigned)hx | ((unsigned)hy << 16);
        *reinterpret_cast<unsigned*>(&agl[nl][lane * 2]) = (unsigned)lx | ((unsigned)ly << 16);
    }

    // ---- phase 1c: stage h rows, split fp32 -> bf16 hi/lo in LDS ----
    {
        const int r = tid >> 4, c0 = (tid & 15) * 8;
        float v[8];
        const float* hp = Hf + (size_t)(row0 + r) * HDIM + c0;
        *reinterpret_cast<float4*>(&v[0]) = *reinterpret_cast<const float4*>(hp);
        *reinterpret_cast<float4*>(&v[4]) = *reinterpret_cast<const float4*>(hp + 4);
        bf16x8 hi, lo;
        split8(v, hi, lo);
        *reinterpret_cast<bf16x8*>(&hhh[r][c0]) = hi;
        *reinterpret_cast<bf16x8*>(&hhl[r][c0]) = lo;
    }
    __syncthreads();

    // ---- phase 2: GEMM + gates; wave owns 16 cols (cs), 32 rows ----
    const int lr = lane & 15, lk = (lane >> 4) * 8, cs = wave * 16;
    f32x4 accI[2][3], accH[2][3];
#pragma unroll
    for (int rf = 0; rf < 2; ++rf)
#pragma unroll
        for (int g = 0; g < 3; ++g) { accI[rf][g] = (f32x4)0.f; accH[rf][g] = (f32x4)0.f; }
#pragma unroll
    for (int kc = 0; kc < 4; ++kc) {
        bf16x8 ga[2], gl[2], ha[2], hl[2];
#pragma unroll
        for (int rf = 0; rf < 2; ++rf) {
            const int rr = rf * 16 + lr, cc = kc * 32 + lk;
            ga[rf] = *reinterpret_cast<const bf16x8*>(&agh[rr][cc]);
            gl[rf] = *reinterpret_cast<const bf16x8*>(&agl[rr][cc]);
            ha[rf] = *reinterpret_cast<const bf16x8*>(&hhh[rr][cc]);
            hl[rf] = *reinterpret_cast<const bf16x8*>(&hhl[rr][cc]);
        }
#pragma unroll
        for (int g = 0; g < 3; ++g) {
            const size_t bo = (size_t)(g * 128 + cs + lr) * HDIM + kc * 32 + lk;
            bf16x8 fh = ld8(Wfhi + bo), fl = ld8(Wflo + bo);
            bf16x8 wh = ld8(Whhi + bo), wl = ld8(Whlo + bo);
#pragma unroll
            for (int rf = 0; rf < 2; ++rf) {
                MFMA(accI[rf][g], ga[rf], fh); MFMA(accI[rf][g], ga[rf], fl); MFMA(accI[rf][g], gl[rf], fh);
                MFMA(accH[rf][g], ha[rf], wh); MFMA(accH[rf][g], ha[rf], wl); MFMA(accH[rf][g], hl[rf], wh);
            }
        }
    }
    const int c = cs + lr;
    const float bir = bih[c], biz = bih[128 + c], bin = bih[256 + c];
    const float bhr = bhh[c], bhz = bhh[128 + c], bhn = bhh[256 + c];
#pragma unroll
    for (int rf = 0; rf < 2; ++rf)
#pragma unroll
        for (int rg = 0; rg < 4; ++rg) {
            const int row = row0 + rf * 16 + (lane >> 4) * 4 + rg;
            float gir = accI[rf][0][rg] + bir;
            float giz = accI[rf][1][rg] + biz;
            float gin = accI[rf][2][rg] + bin;
            float ghr = accH[rf][0][rg] + bhr;
            float ghz = accH[rf][1][rg] + bhz;
            float ghn = accH[rf][2][rg] + bhn;
            float r = 1.f / (1.f + expf(-(gir + ghr)));
            float z = 1.f / (1.f + expf(-(giz + ghz)));
            float nn = tanhf(gin + r * ghn);
            size_t o = (size_t)row * HDIM + c;
            float hold = Hf[o];
            Hnf[o] = (1.f - z) * nn + z * hold;
        }
}

// ---------------- CSR build -------------------------------------------------
__global__ void zero_int(int* p, int n) {
    int i = blockIdx.x * 256 + threadIdx.x;
    if (i < n) p[i] = 0;
}

__global__ void hist_kernel(const int* __restrict__ dst, int* __restrict__ cnt, int E) {
    int e = blockIdx.x * 256 + threadIdx.x;
    if (e < E) atomicAdd(&cnt[dst[e]], 1);
}

// single-block chunked exclusive scan with wave shuffles
__global__ __launch_bounds__(1024) void scan_kernel(int* __restrict__ cnt_cursor,
                                                    int* __restrict__ row_off, int n) {
    __shared__ int wsum[16];
    __shared__ int carry_s;
    const int tid = threadIdx.x, lane = tid & 63, wv = tid >> 6;
    if (tid == 0) carry_s = 0;
    __syncthreads();
    for (int base = 0; base < n; base += 1024) {
        int i = base + tid;
        int v = (i < n) ? cnt_cursor[i] : 0;
        int x = v;
#pragma unroll
        for (int off = 1; off < 64; off <<= 1) {
            int t = __shfl_up(x, off);
            if (lane >= off) x += t;
        }
        if (lane == 63) wsum[wv] = x;
        __syncthreads();
        if (wv == 0 && lane < 16) {
            int s = wsum[lane];
#pragma unroll
            for (int off = 1; off < 16; off <<= 1) {
                int t = __shfl_up(s, off);
                if (lane >= off) s += t;
            }
            wsum[lane] = s;
        }
        __syncthreads();
        int wbase = (wv == 0) ? 0 : wsum[wv - 1];
        int carry = carry_s;
        int total = wsum[15];
        int excl = carry + wbase + x - v;
        if (i < n) { row_off[i] = excl; cnt_cursor[i] = excl; }
        __syncthreads();
        if (tid == 0) carry_s = carry + total;
        __syncthreads();
    }
    if (tid == 0) row_off[n] = carry_s;
}

__global__ void scatter_kernel(const int* __restrict__ src, const int* __restrict__ dst,
                               int* __restrict__ cursor, int* __restrict__ ssrc, int E) {
    int e = blockIdx.x * 256 + threadIdx.x;
    if (e < E) {
        int p = atomicAdd(&cursor[dst[e]], 1);
        ssrc[p] = src[e];
    }
}

// ---------------- mean-pool + relu ------------------------------------------
__global__ __launch_bounds__(256) void pool_k(const float* __restrict__ Hf,
                                              const int* __restrict__ batch,
                                              float* __restrict__ pooled, int M) {
    __shared__ int lo_s, hi_s;
    __shared__ float smx[256], smy[256];
    int g = blockIdx.x;
    if (threadIdx.x == 0) {
        int lo = 0, hi = M;
        while (lo < hi) { int mid = (lo + hi) >> 1; if (batch[mid] < g) lo = mid + 1; else hi = mid; }
        lo_s = lo;
        int lo2 = lo, hi2 = M;
        while (lo2 < hi2) { int mid = (lo2 + hi2) >> 1; if (batch[mid] < g + 1) lo2 = mid + 1; else hi2 = mid; }
        hi_s = lo2;
    }
    __syncthreads();
    int lo = lo_s, hi = hi_s;
    int c2 = threadIdx.x & 63, quarter = threadIdx.x >> 6;
    float ax = 0.f, ay = 0.f;
    for (int i = lo + quarter; i < hi; i += 4) {
        float2 v = *reinterpret_cast<const float2*>(Hf + (size_t)i * HDIM + c2 * 2);
        ax += v.x; ay += v.y;
    }
    smx[threadIdx.x] = ax; smy[threadIdx.x] = ay;
    __syncthreads();
    if (quarter == 0) {
        float sx = smx[c2] + smx[c2 + 64] + smx[c2 + 128] + smx[c2 + 192];
        float sy = smy[c2] + smy[c2 + 64] + smy[c2 + 128] + smy[c2 + 192];
        float cnt = (float)(hi - lo); if (cnt < 1.f) cnt = 1.f;
        pooled[g * HDIM + c2 * 2]     = fmaxf(sx / cnt, 0.f);
        pooled[g * HDIM + c2 * 2 + 1] = fmaxf(sy / cnt, 0.f);
    }
}

// ---------------- prediction head -------------------------------------------
__global__ void pred_kernel(const float* __restrict__ pa, const float* __restrict__ pv,
                            const float* __restrict__ pW, const float* __restrict__ pb,
                            float* __restrict__ out) {
    int g = blockIdx.x, lane = threadIdx.x; // 64 threads
    float s = pa[g * HDIM + lane] * pW[lane]
            + pa[g * HDIM + 64 + lane] * pW[64 + lane]
            + pv[g * HDIM + lane] * pW[HDIM + lane]
            + pv[g * HDIM + 64 + lane] * pW[192 + lane];
    for (int off = 32; off; off >>= 1) s += __shfl_down(s, off);
    if (lane == 0) out[g] = s + pb[0];
}

extern "C" void kernel_launch(void* const* d_in, const int* in_sizes, int n_in,
                              void* d_out, int out_size, void* d_ws, size_t ws_size,
                              hipStream_t stream) {
    const float* atom_x   = (const float*)d_in[0];
    const float* voro_x   = (const float*)d_in[1];
    const int*   atom_ei  = (const int*)d_in[2];
    const int*   voro_ei  = (const int*)d_in[3];
    const int*   batch    = (const int*)d_in[4];
    const float* W_at_in  = (const float*)d_in[5];
    const float* W_vo_in  = (const float*)d_in[6];
    const float* atom_W   = (const float*)d_in[7];
    const float* voro_W   = (const float*)d_in[8];
    const float* atom_Wih = (const float*)d_in[9];
    const float* atom_Whh = (const float*)d_in[10];
    const float* atom_bih = (const float*)d_in[11];
    const float* atom_bhh = (const float*)d_in[12];
    const float* voro_Wih = (const float*)d_in[13];
    const float* voro_Whh = (const float*)d_in[14];
    const float* voro_bih = (const float*)d_in[15];
    const float* voro_bhh = (const float*)d_in[16];
    const float* pred_W   = (const float*)d_in[17];
    const float* pred_b   = (const float*)d_in[18];
    float* out = (float*)d_out;

    const int Nn = in_sizes[4];
    const int Ee = in_sizes[2] / 2;
    const int Gg = out_size;
    const int Npad = (Nn + 31) & ~31;

    char* base = (char*)d_ws;
    size_t off = 0;
    auto alloc = [&](size_t bytes) -> char* {
        char* p = base + off;
        off = (off + bytes + 255) & ~(size_t)255;
        return p;
    };

    float* Hf  = (float*)alloc((size_t)Npad * HDIM * 4);
    float* Hnf = (float*)alloc((size_t)Npad * HDIM * 4);
    // X hi/lo alias Hnf (X is dead once embed finishes; first step then writes Hnf)
    u16* Xhi = (u16*)Hnf;
    u16* Xlo = Xhi + (size_t)Npad * 64;
    u16 *WfHi[2], *WfLo[2], *WhHi[2], *WhLo[2], *WnHi[2], *WnLo[2];
    for (int t = 0; t < 2; ++t) {
        WfHi[t] = (u16*)alloc(4 * 49152 * 2); WfLo[t] = (u16*)alloc(4 * 49152 * 2);
        WhHi[t] = (u16*)alloc(384 * 128 * 2); WhLo[t] = (u16*)alloc(384 * 128 * 2);
        WnHi[t] = (u16*)alloc(128 * 64 * 2);  WnLo[t] = (u16*)alloc(128 * 64 * 2);
    }
    float* pooledA = (float*)alloc((size_t)Gg * HDIM * 4);
    float* pooledV = (float*)alloc((size_t)Gg * HDIM * 4);
    int* row_off = (int*)alloc((size_t)(Nn + 1) * 4);
    int* cursor  = (int*)alloc((size_t)Nn * 4);
    int* ssrc    = (int*)alloc((size_t)Ee * 4);

    const float* xs[2]   = {atom_x, voro_x};
    const float* Win[2]  = {W_at_in, W_vo_in};
    const int*   ei[2]   = {atom_ei, voro_ei};
    const float* Wst[2]  = {atom_W, voro_W};
    const float* Wih[2]  = {atom_Wih, voro_Wih};
    const float* Whh[2]  = {atom_Whh, voro_Whh};
    const float* bihp[2] = {atom_bih, voro_bih};
    const float* bhhp[2] = {atom_bhh, voro_bhh};
    float* pool2[2]      = {pooledA, pooledV};

    // weight prep
    for (int t = 0; t < 2; ++t) {
        prep_wfull<<<dim3(192, 4), 256, 0, stream>>>(Wst[t], Wih[t], WfHi[t], WfLo[t]);
        prep_split<<<192, 256, 0, stream>>>(Whh[t], WhHi[t], WhLo[t], 384 * 128);
        prep_win<<<32, 256, 0, stream>>>(Win[t], WnHi[t], WnLo[t]);
    }

    const int eb  = (Ee + 255) / 256;
    const int nb  = (Nn + 255) / 256;
    const int gbs = Npad / 32;

    for (int t = 0; t < 2; ++t) {
        split_x<<<(Npad * 64 + 255) / 256, 256, 0, stream>>>(xs[t], Xhi, Xlo, Nn * 64, Npad * 64);
        embed_k<<<gbs, 256, 0, stream>>>(Xhi, Xlo, WnHi[t], WnLo[t], Hf);

        zero_int<<<nb, 256, 0, stream>>>(cursor, Nn);
        hist_kernel<<<eb, 256, 0, stream>>>(ei[t] + Ee, cursor, Ee);
        scan_kernel<<<1, 1024, 0, stream>>>(cursor, row_off, Nn);
        scatter_kernel<<<eb, 256, 0, stream>>>(ei[t], ei[t] + Ee, cursor, ssrc, Ee);

        float *hA = Hf, *hB = Hnf;
        for (int s = 0; s < 4; ++s) {
            step_k<<<gbs, 512, 0, stream>>>(hA, row_off, ssrc,
                                            WfHi[t] + (size_t)s * 49152, WfLo[t] + (size_t)s * 49152,
                                            WhHi[t], WhLo[t], bihp[t], bhhp[t], hB, Nn);
            float* tp = hA; hA = hB; hB = tp;
        }
        pool_k<<<Gg, 256, 0, stream>>>(hA, batch, pool2[t], Nn);
    }
    pred_kernel<<<Gg, 64, 0, stream>>>(pooledA, pooledV, pred_W, pred_b, out);
}

// Round 7
// 1248.352 us; speedup vs baseline: 3.3272x; 1.2062x over previous
//
#include <hip/hip_runtime.h>
#include <math.h>

#define HDIM 128
typedef unsigned short u16;
typedef __attribute__((ext_vector_type(8))) short bf16x8;
typedef __attribute__((ext_vector_type(4))) float f32x4;

__device__ __forceinline__ u16 f2bf(float x) {
    unsigned u = __float_as_uint(x);
    u = (u + 0x7FFFu + ((u >> 16) & 1u)) >> 16;
    return (u16)u;
}
__device__ __forceinline__ float bf2f(u16 h) {
    return __uint_as_float(((unsigned)h) << 16);
}
__device__ __forceinline__ bf16x8 ld8(const u16* p) {
    return *reinterpret_cast<const bf16x8*>(p);
}
// split 8 fp32 -> bf16 hi (round-nearest) + bf16 lo (truncated remainder)
__device__ __forceinline__ void split8(const float* v, bf16x8& hi, bf16x8& lo) {
#pragma unroll
    for (int j = 0; j < 8; ++j) {
        unsigned u = __float_as_uint(v[j]);
        unsigned h = (u + 0x7FFFu + ((u >> 16) & 1u)) >> 16;
        float rem = v[j] - __uint_as_float(h << 16);
        hi[j] = (short)h;
        lo[j] = (short)(__float_as_uint(rem) >> 16);
    }
}
#define MFMA(acc, a, b) acc = __builtin_amdgcn_mfma_f32_16x16x32_bf16(a, b, acc, 0, 0, 0)

// ---------------- weight prep -----------------------------------------------
__global__ __launch_bounds__(256) void prep_wfull(const float* __restrict__ Ws,
                                                  const float* __restrict__ Wih,
                                                  u16* __restrict__ hi, u16* __restrict__ lo) {
    int s = blockIdx.y;
    int idx = blockIdx.x * 256 + threadIdx.x;   // [0, 49152)
    int c2 = idx >> 7, r = idx & 127;
    const float* wr = Ws + (size_t)s * 16384 + (size_t)r * 128;
    const float* wc = Wih + (size_t)c2 * 128;
    float acc = 0.f;
#pragma unroll 8
    for (int k = 0; k < 128; k += 4) {
        float4 a = *reinterpret_cast<const float4*>(wr + k);
        float4 b = *reinterpret_cast<const float4*>(wc + k);
        acc += a.x * b.x + a.y * b.y + a.z * b.z + a.w * b.w;
    }
    size_t o = (size_t)s * 49152 + idx;
    u16 h = f2bf(acc);
    hi[o] = h; lo[o] = f2bf(acc - bf2f(h));
}

__global__ __launch_bounds__(256) void prep_split(const float* __restrict__ W,
                                                  u16* __restrict__ hi, u16* __restrict__ lo, int n) {
    int i = blockIdx.x * 256 + threadIdx.x;
    if (i < n) { float v = W[i]; u16 h = f2bf(v); hi[i] = h; lo[i] = f2bf(v - bf2f(h)); }
}

// WinT[r][c] = W_in[c][r], [128][64]
__global__ __launch_bounds__(256) void prep_win(const float* __restrict__ W,
                                                u16* __restrict__ hi, u16* __restrict__ lo) {
    int idx = blockIdx.x * 256 + threadIdx.x;        // 0..8191
    int r = idx >> 6, c = idx & 63;
    float v = W[(size_t)c * 128 + r];
    u16 h = f2bf(v);
    hi[idx] = h; lo[idx] = f2bf(v - bf2f(h));
}

// split x -> padded bf16 hi/lo (both graphs via blockIdx.y)
__global__ __launch_bounds__(256) void split_x2(const float* __restrict__ x0, const float* __restrict__ x1,
                                                u16* __restrict__ hi0, u16* __restrict__ lo0,
                                                u16* __restrict__ hi1, u16* __restrict__ lo1,
                                                int n, int ntot) {
    int i = blockIdx.x * 256 + threadIdx.x;
    if (i >= ntot) return;
    const float* x = blockIdx.y ? x1 : x0;
    u16* hi = blockIdx.y ? hi1 : hi0;
    u16* lo = blockIdx.y ? lo1 : lo0;
    float v = (i < n) ? x[i] : 0.f;
    u16 h = f2bf(v);
    hi[i] = h; lo[i] = f2bf(v - bf2f(h));
}

// ---------------- embed: Hf = tanh(X @ Win), K=64, both graphs --------------
__global__ __launch_bounds__(256) void embed_k(const u16* __restrict__ Xhi0, const u16* __restrict__ Xlo0,
                                               const u16* __restrict__ Xhi1, const u16* __restrict__ Xlo1,
                                               const u16* __restrict__ Bhi0, const u16* __restrict__ Blo0,
                                               const u16* __restrict__ Bhi1, const u16* __restrict__ Blo1,
                                               float* __restrict__ Hf0, float* __restrict__ Hf1) {
    const int by = blockIdx.y;
    const u16* Xhi = by ? Xhi1 : Xhi0;  const u16* Xlo = by ? Xlo1 : Xlo0;
    const u16* Bhi = by ? Bhi1 : Bhi0;  const u16* Blo = by ? Blo1 : Blo0;
    float* Hf = by ? Hf1 : Hf0;
    const int tid = threadIdx.x, wave = tid >> 6, lane = tid & 63;
    const int row0 = blockIdx.x * 32, cs = wave * 32;
    const int lr = lane & 15, lk = (lane >> 4) * 8;
    f32x4 acc[2][2];
#pragma unroll
    for (int i = 0; i < 2; ++i)
#pragma unroll
        for (int j = 0; j < 2; ++j) acc[i][j] = (f32x4)0.f;
#pragma unroll
    for (int kc = 0; kc < 2; ++kc) {
        const size_t ao = (size_t)(row0 + lr) * 64 + kc * 32 + lk;
        bf16x8 ah0 = ld8(Xhi + ao), ah1 = ld8(Xhi + ao + 16 * 64);
        bf16x8 al0 = ld8(Xlo + ao), al1 = ld8(Xlo + ao + 16 * 64);
#pragma unroll
        for (int cf = 0; cf < 2; ++cf) {
            const size_t bo = (size_t)(cs + cf * 16 + lr) * 64 + kc * 32 + lk;
            bf16x8 bh = ld8(Bhi + bo), bl = ld8(Blo + bo);
            MFMA(acc[0][cf], ah0, bh); MFMA(acc[0][cf], ah0, bl); MFMA(acc[0][cf], al0, bh);
            MFMA(acc[1][cf], ah1, bh); MFMA(acc[1][cf], ah1, bl); MFMA(acc[1][cf], al1, bh);
        }
    }
#pragma unroll
    for (int rf = 0; rf < 2; ++rf)
#pragma unroll
        for (int cf = 0; cf < 2; ++cf)
#pragma unroll
            for (int rg = 0; rg < 4; ++rg) {
                int row = row0 + rf * 16 + (lane >> 4) * 4 + rg;
                int col = cs + cf * 16 + lr;
                Hf[(size_t)row * HDIM + col] = tanhf(acc[rf][cf][rg]);
            }
}

// ---------------- fused step: LDS-staged indices, gather, GEMM; 2 graphs ----
// 512 threads = 8 waves; block covers 32 node-rows of graph blockIdx.y.
__global__ __launch_bounds__(512, 4) void step_k(const float* __restrict__ Hf0, const float* __restrict__ Hf1,
                                                 const int* __restrict__ ro0, const int* __restrict__ ro1,
                                                 const int* __restrict__ ss0, const int* __restrict__ ss1,
                                                 const u16* __restrict__ Wf0h, const u16* __restrict__ Wf0l,
                                                 const u16* __restrict__ Wf1h, const u16* __restrict__ Wf1l,
                                                 const u16* __restrict__ Wh0h, const u16* __restrict__ Wh0l,
                                                 const u16* __restrict__ Wh1h, const u16* __restrict__ Wh1l,
                                                 const float* __restrict__ bi0, const float* __restrict__ bh0,
                                                 const float* __restrict__ bi1, const float* __restrict__ bh1,
                                                 float* __restrict__ Hn0, float* __restrict__ Hn1, int Nn) {
    __shared__ u16 agh[32][136];
    __shared__ u16 agl[32][136];
    __shared__ u16 hhh[32][136];
    __shared__ u16 hhl[32][136];
    __shared__ int eidx[1024];
    const int by = blockIdx.y;
    const float* Hf = by ? Hf1 : Hf0;
    const int* row_off = by ? ro1 : ro0;
    const int* ssrc = by ? ss1 : ss0;
    const int tid = threadIdx.x, wave = tid >> 6, lane = tid & 63;
    const int row0 = blockIdx.x * 32;

    // ---- phase 0: stage edge indices into LDS ----
    const int rowEnd = (row0 + 32 < Nn) ? row0 + 32 : Nn;
    const int eLo = row_off[row0];
    const int nE = row_off[rowEnd] - eLo;
    for (int i = tid; i < nE && i < 1024; i += 512) eidx[i] = ssrc[eLo + i];
    __syncthreads();

    // ---- phase 1: gather neighbor-sum of h (fp32 register accum) ----
#pragma unroll
    for (int q = 0; q < 4; ++q) {
        const int nl = wave * 4 + q;
        const int node = row0 + nl;
        float ax = 0.f, ay = 0.f;
        if (node < Nn) {
            int lo = row_off[node] - eLo, hi = row_off[node + 1] - eLo;
            int hiS = (hi < 1024) ? hi : 1024;
            int i = lo;
            for (; i + 8 <= hiS; i += 8) {
                float2 v0 = *reinterpret_cast<const float2*>(Hf + (size_t)eidx[i] * HDIM + lane * 2);
                float2 v1 = *reinterpret_cast<const float2*>(Hf + (size_t)eidx[i + 1] * HDIM + lane * 2);
                float2 v2 = *reinterpret_cast<const float2*>(Hf + (size_t)eidx[i + 2] * HDIM + lane * 2);
                float2 v3 = *reinterpret_cast<const float2*>(Hf + (size_t)eidx[i + 3] * HDIM + lane * 2);
                float2 v4 = *reinterpret_cast<const float2*>(Hf + (size_t)eidx[i + 4] * HDIM + lane * 2);
                float2 v5 = *reinterpret_cast<const float2*>(Hf + (size_t)eidx[i + 5] * HDIM + lane * 2);
                float2 v6 = *reinterpret_cast<const float2*>(Hf + (size_t)eidx[i + 6] * HDIM + lane * 2);
                float2 v7 = *reinterpret_cast<const float2*>(Hf + (size_t)eidx[i + 7] * HDIM + lane * 2);
                ax += ((v0.x + v1.x) + (v2.x + v3.x)) + ((v4.x + v5.x) + (v6.x + v7.x));
                ay += ((v0.y + v1.y) + (v2.y + v3.y)) + ((v4.y + v5.y) + (v6.y + v7.y));
            }
            for (; i + 4 <= hiS; i += 4) {
                float2 v0 = *reinterpret_cast<const float2*>(Hf + (size_t)eidx[i] * HDIM + lane * 2);
                float2 v1 = *reinterpret_cast<const float2*>(Hf + (size_t)eidx[i + 1] * HDIM + lane * 2);
                float2 v2 = *reinterpret_cast<const float2*>(Hf + (size_t)eidx[i + 2] * HDIM + lane * 2);
                float2 v3 = *reinterpret_cast<const float2*>(Hf + (size_t)eidx[i + 3] * HDIM + lane * 2);
                ax += (v0.x + v1.x) + (v2.x + v3.x);
                ay += (v0.y + v1.y) + (v2.y + v3.y);
            }
            for (; i < hiS; ++i) {
                float2 v = *reinterpret_cast<const float2*>(Hf + (size_t)eidx[i] * HDIM + lane * 2);
                ax += v.x; ay += v.y;
            }
            for (; i < hi; ++i) {   // LDS overflow fallback (degenerate blocks)
                float2 v = *reinterpret_cast<const float2*>(Hf + (size_t)ssrc[eLo + i] * HDIM + lane * 2);
                ax += v.x; ay += v.y;
            }
        }
        u16 hx = f2bf(ax), hy = f2bf(ay);
        u16 lx = f2bf(ax - bf2f(hx)), ly = f2bf(ay - bf2f(hy));
        *reinterpret_cast<unsigned*>(&agh[nl][lane * 2]) = (unsigned)hx | ((unsigned)hy << 16);
        *reinterpret_cast<unsigned*>(&agl[nl][lane * 2]) = (unsigned)lx | ((unsigned)ly << 16);
    }

    // ---- phase 1c: stage h rows, split fp32 -> bf16 hi/lo in LDS ----
    {
        const int r = tid >> 4, c0 = (tid & 15) * 8;
        float v[8];
        const float* hp = Hf + (size_t)(row0 + r) * HDIM + c0;
        *reinterpret_cast<float4*>(&v[0]) = *reinterpret_cast<const float4*>(hp);
        *reinterpret_cast<float4*>(&v[4]) = *reinterpret_cast<const float4*>(hp + 4);
        bf16x8 hi, lo;
        split8(v, hi, lo);
        *reinterpret_cast<bf16x8*>(&hhh[r][c0]) = hi;
        *reinterpret_cast<bf16x8*>(&hhl[r][c0]) = lo;
    }
    __syncthreads();

    // ---- phase 2: GEMM + gates; wave owns 16 cols (cs), 32 rows ----
    const u16* Wfhi = by ? Wf1h : Wf0h;  const u16* Wflo = by ? Wf1l : Wf0l;
    const u16* Whhi = by ? Wh1h : Wh0h;  const u16* Whlo = by ? Wh1l : Wh0l;
    const float* bih = by ? bi1 : bi0;   const float* bhh = by ? bh1 : bh0;
    float* Hnf = by ? Hn1 : Hn0;
    const int lr = lane & 15, lk = (lane >> 4) * 8, cs = wave * 16;
    f32x4 accI[2][3], accH[2][3];
#pragma unroll
    for (int rf = 0; rf < 2; ++rf)
#pragma unroll
        for (int g = 0; g < 3; ++g) { accI[rf][g] = (f32x4)0.f; accH[rf][g] = (f32x4)0.f; }
#pragma unroll
    for (int kc = 0; kc < 4; ++kc) {
        bf16x8 ga[2], gl[2], ha[2], hl[2];
#pragma unroll
        for (int rf = 0; rf < 2; ++rf) {
            const int rr = rf * 16 + lr, cc = kc * 32 + lk;
            ga[rf] = *reinterpret_cast<const bf16x8*>(&agh[rr][cc]);
            gl[rf] = *reinterpret_cast<const bf16x8*>(&agl[rr][cc]);
            ha[rf] = *reinterpret_cast<const bf16x8*>(&hhh[rr][cc]);
            hl[rf] = *reinterpret_cast<const bf16x8*>(&hhl[rr][cc]);
        }
#pragma unroll
        for (int g = 0; g < 3; ++g) {
            const size_t bo = (size_t)(g * 128 + cs + lr) * HDIM + kc * 32 + lk;
            bf16x8 fh = ld8(Wfhi + bo), fl = ld8(Wflo + bo);
            bf16x8 wh = ld8(Whhi + bo), wl = ld8(Whlo + bo);
#pragma unroll
            for (int rf = 0; rf < 2; ++rf) {
                MFMA(accI[rf][g], ga[rf], fh); MFMA(accI[rf][g], ga[rf], fl); MFMA(accI[rf][g], gl[rf], fh);
                MFMA(accH[rf][g], ha[rf], wh); MFMA(accH[rf][g], ha[rf], wl); MFMA(accH[rf][g], hl[rf], wh);
            }
        }
    }
    const int c = cs + lr;
    const float bir = bih[c], biz = bih[128 + c], bin = bih[256 + c];
    const float bhr = bhh[c], bhz = bhh[128 + c], bhn = bhh[256 + c];
#pragma unroll
    for (int rf = 0; rf < 2; ++rf)
#pragma unroll
        for (int rg = 0; rg < 4; ++rg) {
            const int row = row0 + rf * 16 + (lane >> 4) * 4 + rg;
            float gir = accI[rf][0][rg] + bir;
            float giz = accI[rf][1][rg] + biz;
            float gin = accI[rf][2][rg] + bin;
            float ghr = accH[rf][0][rg] + bhr;
            float ghz = accH[rf][1][rg] + bhz;
            float ghn = accH[rf][2][rg] + bhn;
            float r = 1.f / (1.f + expf(-(gir + ghr)));
            float z = 1.f / (1.f + expf(-(giz + ghz)));
            float nn = tanhf(gin + r * ghn);
            size_t o = (size_t)row * HDIM + c;
            float hold = Hf[o];
            Hnf[o] = (1.f - z) * nn + z * hold;
        }
}

// ---------------- CSR build (both graphs via blockIdx.y) --------------------
__global__ void zero_int2(int* p0, int* p1, int n) {
    int i = blockIdx.x * 256 + threadIdx.x;
    int* p = blockIdx.y ? p1 : p0;
    if (i < n) p[i] = 0;
}

__global__ void hist_k2(const int* __restrict__ d0, const int* __restrict__ d1,
                        int* __restrict__ c0, int* __restrict__ c1, int E) {
    int e = blockIdx.x * 256 + threadIdx.x;
    const int* dst = blockIdx.y ? d1 : d0;
    int* cnt = blockIdx.y ? c1 : c0;
    if (e < E) atomicAdd(&cnt[dst[e]], 1);
}

// grid.x = 2: block b scans graph b
__global__ __launch_bounds__(1024) void scan_k2(int* __restrict__ c0, int* __restrict__ r0,
                                                int* __restrict__ c1, int* __restrict__ r1, int n) {
    int* cnt_cursor = blockIdx.x ? c1 : c0;
    int* row_off = blockIdx.x ? r1 : r0;
    __shared__ int wsum[16];
    __shared__ int carry_s;
    const int tid = threadIdx.x, lane = tid & 63, wv = tid >> 6;
    if (tid == 0) carry_s = 0;
    __syncthreads();
    for (int base = 0; base < n; base += 1024) {
        int i = base + tid;
        int v = (i < n) ? cnt_cursor[i] : 0;
        int x = v;
#pragma unroll
        for (int off = 1; off < 64; off <<= 1) {
            int t = __shfl_up(x, off);
            if (lane >= off) x += t;
        }
        if (lane == 63) wsum[wv] = x;
        __syncthreads();
        if (wv == 0 && lane < 16) {
            int s = wsum[lane];
#pragma unroll
            for (int off = 1; off < 16; off <<= 1) {
                int t = __shfl_up(s, off);
                if (lane >= off) s += t;
            }
            wsum[lane] = s;
        }
        __syncthreads();
        int wbase = (wv == 0) ? 0 : wsum[wv - 1];
        int carry = carry_s;
        int total = wsum[15];
        int excl = carry + wbase + x - v;
        if (i < n) { row_off[i] = excl; cnt_cursor[i] = excl; }
        __syncthreads();
        if (tid == 0) carry_s = carry + total;
        __syncthreads();
    }
    if (tid == 0) row_off[n] = carry_s;
}

__global__ void scatter_k2(const int* __restrict__ s0, const int* __restrict__ d0,
                           const int* __restrict__ s1, const int* __restrict__ d1,
                           int* __restrict__ c0, int* __restrict__ c1,
                           int* __restrict__ o0, int* __restrict__ o1, int E) {
    int e = blockIdx.x * 256 + threadIdx.x;
    const int* src = blockIdx.y ? s1 : s0;
    const int* dst = blockIdx.y ? d1 : d0;
    int* cursor = blockIdx.y ? c1 : c0;
    int* ssrc = blockIdx.y ? o1 : o0;
    if (e < E) {
        int p = atomicAdd(&cursor[dst[e]], 1);
        ssrc[p] = src[e];
    }
}

// ---------------- mean-pool + relu (both graphs) ----------------------------
__global__ __launch_bounds__(256) void pool_k(const float* __restrict__ H0, const float* __restrict__ H1,
                                              const int* __restrict__ batch,
                                              float* __restrict__ p0, float* __restrict__ p1, int M) {
    const float* Hf = blockIdx.y ? H1 : H0;
    float* pooled = blockIdx.y ? p1 : p0;
    __shared__ int lo_s, hi_s;
    __shared__ float smx[256], smy[256];
    int g = blockIdx.x;
    if (threadIdx.x == 0) {
        int lo = 0, hi = M;
        while (lo < hi) { int mid = (lo + hi) >> 1; if (batch[mid] < g) lo = mid + 1; else hi = mid; }
        lo_s = lo;
        int lo2 = lo, hi2 = M;
        while (lo2 < hi2) { int mid = (lo2 + hi2) >> 1; if (batch[mid] < g + 1) lo2 = mid + 1; else hi2 = mid; }
        hi_s = lo2;
    }
    __syncthreads();
    int lo = lo_s, hi = hi_s;
    int c2 = threadIdx.x & 63, quarter = threadIdx.x >> 6;
    float ax = 0.f, ay = 0.f;
    for (int i = lo + quarter; i < hi; i += 4) {
        float2 v = *reinterpret_cast<const float2*>(Hf + (size_t)i * HDIM + c2 * 2);
        ax += v.x; ay += v.y;
    }
    smx[threadIdx.x] = ax; smy[threadIdx.x] = ay;
    __syncthreads();
    if (quarter == 0) {
        float sx = smx[c2] + smx[c2 + 64] + smx[c2 + 128] + smx[c2 + 192];
        float sy = smy[c2] + smy[c2 + 64] + smy[c2 + 128] + smy[c2 + 192];
        float cnt = (float)(hi - lo); if (cnt < 1.f) cnt = 1.f;
        pooled[g * HDIM + c2 * 2]     = fmaxf(sx / cnt, 0.f);
        pooled[g * HDIM + c2 * 2 + 1] = fmaxf(sy / cnt, 0.f);
    }
}

// ---------------- prediction head -------------------------------------------
__global__ void pred_kernel(const float* __restrict__ pa, const float* __restrict__ pv,
                            const float* __restrict__ pW, const float* __restrict__ pb,
                            float* __restrict__ out) {
    int g = blockIdx.x, lane = threadIdx.x; // 64 threads
    float s = pa[g * HDIM + lane] * pW[lane]
            + pa[g * HDIM + 64 + lane] * pW[64 + lane]
            + pv[g * HDIM + lane] * pW[HDIM + lane]
            + pv[g * HDIM + 64 + lane] * pW[192 + lane];
    for (int off = 32; off; off >>= 1) s += __shfl_down(s, off);
    if (lane == 0) out[g] = s + pb[0];
}

extern "C" void kernel_launch(void* const* d_in, const int* in_sizes, int n_in,
                              void* d_out, int out_size, void* d_ws, size_t ws_size,
                              hipStream_t stream) {
    const float* atom_x   = (const float*)d_in[0];
    const float* voro_x   = (const float*)d_in[1];
    const int*   atom_ei  = (const int*)d_in[2];
    const int*   voro_ei  = (const int*)d_in[3];
    const int*   batch    = (const int*)d_in[4];
    const float* W_at_in  = (const float*)d_in[5];
    const float* W_vo_in  = (const float*)d_in[6];
    const float* atom_W   = (const float*)d_in[7];
    const float* voro_W   = (const float*)d_in[8];
    const float* atom_Wih = (const float*)d_in[9];
    const float* atom_Whh = (const float*)d_in[10];
    const float* atom_bih = (const float*)d_in[11];
    const float* atom_bhh = (const float*)d_in[12];
    const float* voro_Wih = (const float*)d_in[13];
    const float* voro_Whh = (const float*)d_in[14];
    const float* voro_bih = (const float*)d_in[15];
    const float* voro_bhh = (const float*)d_in[16];
    const float* pred_W   = (const float*)d_in[17];
    const float* pred_b   = (const float*)d_in[18];
    float* out = (float*)d_out;

    const int Nn = in_sizes[4];
    const int Ee = in_sizes[2] / 2;
    const int Gg = out_size;
    const int Npad = (Nn + 31) & ~31;

    char* base = (char*)d_ws;
    size_t off = 0;
    auto alloc = [&](size_t bytes) -> char* {
        char* p = base + off;
        off = (off + bytes + 255) & ~(size_t)255;
        return p;
    };

    float *Hf[2], *Hnf[2];
    u16 *Xhi[2], *Xlo[2];
    u16 *WfHi[2], *WfLo[2], *WhHi[2], *WhLo[2], *WnHi[2], *WnLo[2];
    int *row_off[2], *cursor[2], *ssrc[2];
    for (int t = 0; t < 2; ++t) {
        Hf[t]  = (float*)alloc((size_t)Npad * HDIM * 4);
        Hnf[t] = (float*)alloc((size_t)Npad * HDIM * 4);
        Xhi[t] = (u16*)Hnf[t];                 // X aliases Hnf (dead after embed)
        Xlo[t] = Xhi[t] + (size_t)Npad * 64;
        WfHi[t] = (u16*)alloc(4 * 49152 * 2); WfLo[t] = (u16*)alloc(4 * 49152 * 2);
        WhHi[t] = (u16*)alloc(384 * 128 * 2); WhLo[t] = (u16*)alloc(384 * 128 * 2);
        WnHi[t] = (u16*)alloc(128 * 64 * 2);  WnLo[t] = (u16*)alloc(128 * 64 * 2);
        row_off[t] = (int*)alloc((size_t)(Nn + 1) * 4);
        cursor[t]  = (int*)alloc((size_t)Nn * 4);
        ssrc[t]    = (int*)alloc((size_t)Ee * 4);
    }
    float* pooledA = (float*)alloc((size_t)Gg * HDIM * 4);
    float* pooledV = (float*)alloc((size_t)Gg * HDIM * 4);

    const float* Wst[2] = {atom_W, voro_W};
    const float* Wih[2] = {atom_Wih, voro_Wih};
    const float* Whh[2] = {atom_Whh, voro_Whh};
    const float* Win[2] = {W_at_in, W_vo_in};

    // weight prep
    for (int t = 0; t < 2; ++t) {
        prep_wfull<<<dim3(192, 4), 256, 0, stream>>>(Wst[t], Wih[t], WfHi[t], WfLo[t]);
        prep_split<<<192, 256, 0, stream>>>(Whh[t], WhHi[t], WhLo[t], 384 * 128);
        prep_win<<<32, 256, 0, stream>>>(Win[t], WnHi[t], WnLo[t]);
    }

    const int eb  = (Ee + 255) / 256;
    const int nb  = (Nn + 255) / 256;
    const int gbs = Npad / 32;

    split_x2<<<dim3((Npad * 64 + 255) / 256, 2), 256, 0, stream>>>(
        atom_x, voro_x, Xhi[0], Xlo[0], Xhi[1], Xlo[1], Nn * 64, Npad * 64);
    embed_k<<<dim3(gbs, 2), 256, 0, stream>>>(Xhi[0], Xlo[0], Xhi[1], Xlo[1],
                                              WnHi[0], WnLo[0], WnHi[1], WnLo[1], Hf[0], Hf[1]);

    zero_int2<<<dim3(nb, 2), 256, 0, stream>>>(cursor[0], cursor[1], Nn);
    hist_k2<<<dim3(eb, 2), 256, 0, stream>>>(atom_ei + Ee, voro_ei + Ee, cursor[0], cursor[1], Ee);
    scan_k2<<<2, 1024, 0, stream>>>(cursor[0], row_off[0], cursor[1], row_off[1], Nn);
    scatter_k2<<<dim3(eb, 2), 256, 0, stream>>>(atom_ei, atom_ei + Ee, voro_ei, voro_ei + Ee,
                                                cursor[0], cursor[1], ssrc[0], ssrc[1], Ee);

    float *hA0 = Hf[0], *hB0 = Hnf[0], *hA1 = Hf[1], *hB1 = Hnf[1];
    for (int s = 0; s < 4; ++s) {
        step_k<<<dim3(gbs, 2), 512, 0, stream>>>(
            hA0, hA1, row_off[0], row_off[1], ssrc[0], ssrc[1],
            WfHi[0] + (size_t)s * 49152, WfLo[0] + (size_t)s * 49152,
            WfHi[1] + (size_t)s * 49152, WfLo[1] + (size_t)s * 49152,
            WhHi[0], WhLo[0], WhHi[1], WhLo[1],
            atom_bih, atom_bhh, voro_bih, voro_bhh,
            hB0, hB1, Nn);
        float* tp;
        tp = hA0; hA0 = hB0; hB0 = tp;
        tp = hA1; hA1 = hB1; hB1 = tp;
    }
    pool_k<<<dim3(Gg, 2), 256, 0, stream>>>(hA0, hA1, batch, pooledA, pooledV, Nn);
    pred_kernel<<<Gg, 64, 0, stream>>>(pooledA, pooledV, pred_W, pred_b, out);
}

// Round 8
// 1165.660 us; speedup vs baseline: 3.5632x; 1.0709x over previous
//
#include <hip/hip_runtime.h>
#include <hip/hip_fp16.h>
#include <math.h>

#define HDIM 128
typedef unsigned short u16;
typedef __attribute__((ext_vector_type(8))) short bf16x8;
typedef __attribute__((ext_vector_type(4))) float f32x4;

__device__ __forceinline__ u16 f2bf(float x) {
    unsigned u = __float_as_uint(x);
    u = (u + 0x7FFFu + ((u >> 16) & 1u)) >> 16;
    return (u16)u;
}
__device__ __forceinline__ float bf2f(u16 h) {
    return __uint_as_float(((unsigned)h) << 16);
}
__device__ __forceinline__ bf16x8 ld8(const u16* p) {
    return *reinterpret_cast<const bf16x8*>(p);
}
__device__ __forceinline__ void split8(const float* v, bf16x8& hi, bf16x8& lo) {
#pragma unroll
    for (int j = 0; j < 8; ++j) {
        unsigned u = __float_as_uint(v[j]);
        unsigned h = (u + 0x7FFFu + ((u >> 16) & 1u)) >> 16;
        float rem = v[j] - __uint_as_float(h << 16);
        hi[j] = (short)h;
        lo[j] = (short)(__float_as_uint(rem) >> 16);
    }
}
__device__ __forceinline__ float2 up2(unsigned u) {
    __half2 h = *reinterpret_cast<__half2*>(&u);
    float2 f; f.x = __low2float(h); f.y = __high2float(h); return f;
}
__device__ __forceinline__ u16 f2h(float x) {
    __half t = __float2half(x);
    return *reinterpret_cast<u16*>(&t);
}
#define MFMA(acc, a, b) acc = __builtin_amdgcn_mfma_f32_16x16x32_bf16(a, b, acc, 0, 0, 0)

// ---------------- weight prep -----------------------------------------------
__global__ __launch_bounds__(256) void prep_wfull(const float* __restrict__ Ws,
                                                  const float* __restrict__ Wih,
                                                  u16* __restrict__ hi, u16* __restrict__ lo) {
    int s = blockIdx.y;
    int idx = blockIdx.x * 256 + threadIdx.x;   // [0, 49152)
    int c2 = idx >> 7, r = idx & 127;
    const float* wr = Ws + (size_t)s * 16384 + (size_t)r * 128;
    const float* wc = Wih + (size_t)c2 * 128;
    float acc = 0.f;
#pragma unroll 8
    for (int k = 0; k < 128; k += 4) {
        float4 a = *reinterpret_cast<const float4*>(wr + k);
        float4 b = *reinterpret_cast<const float4*>(wc + k);
        acc += a.x * b.x + a.y * b.y + a.z * b.z + a.w * b.w;
    }
    size_t o = (size_t)s * 49152 + idx;
    u16 h = f2bf(acc);
    hi[o] = h; lo[o] = f2bf(acc - bf2f(h));
}

__global__ __launch_bounds__(256) void prep_split(const float* __restrict__ W,
                                                  u16* __restrict__ hi, u16* __restrict__ lo, int n) {
    int i = blockIdx.x * 256 + threadIdx.x;
    if (i < n) { float v = W[i]; u16 h = f2bf(v); hi[i] = h; lo[i] = f2bf(v - bf2f(h)); }
}

// WinT[r][c] = W_in[c][r], [128][64]
__global__ __launch_bounds__(256) void prep_win(const float* __restrict__ W,
                                                u16* __restrict__ hi, u16* __restrict__ lo) {
    int idx = blockIdx.x * 256 + threadIdx.x;        // 0..8191
    int r = idx >> 6, c = idx & 63;
    float v = W[(size_t)c * 128 + r];
    u16 h = f2bf(v);
    hi[idx] = h; lo[idx] = f2bf(v - bf2f(h));
}

// split x -> padded bf16 hi/lo (both graphs via blockIdx.y)
__global__ __launch_bounds__(256) void split_x2(const float* __restrict__ x0, const float* __restrict__ x1,
                                                u16* __restrict__ hi0, u16* __restrict__ lo0,
                                                u16* __restrict__ hi1, u16* __restrict__ lo1,
                                                int n, int ntot) {
    int i = blockIdx.x * 256 + threadIdx.x;
    if (i >= ntot) return;
    const float* x = blockIdx.y ? x1 : x0;
    u16* hi = blockIdx.y ? hi1 : hi0;
    u16* lo = blockIdx.y ? lo1 : lo0;
    float v = (i < n) ? x[i] : 0.f;
    u16 h = f2bf(v);
    hi[i] = h; lo[i] = f2bf(v - bf2f(h));
}

// ---------------- embed: Hf = tanh(X @ Win), fp32 + fp16 copies -------------
__global__ __launch_bounds__(256) void embed_k(const u16* __restrict__ Xhi0, const u16* __restrict__ Xlo0,
                                               const u16* __restrict__ Xhi1, const u16* __restrict__ Xlo1,
                                               const u16* __restrict__ Bhi0, const u16* __restrict__ Blo0,
                                               const u16* __restrict__ Bhi1, const u16* __restrict__ Blo1,
                                               float* __restrict__ Hf0, float* __restrict__ Hf1,
                                               u16* __restrict__ Hh0, u16* __restrict__ Hh1) {
    const int by = blockIdx.y;
    const u16* Xhi = by ? Xhi1 : Xhi0;  const u16* Xlo = by ? Xlo1 : Xlo0;
    const u16* Bhi = by ? Bhi1 : Bhi0;  const u16* Blo = by ? Blo1 : Blo0;
    float* Hf = by ? Hf1 : Hf0;
    u16* Hh = by ? Hh1 : Hh0;
    const int tid = threadIdx.x, wave = tid >> 6, lane = tid & 63;
    const int row0 = blockIdx.x * 32, cs = wave * 32;
    const int lr = lane & 15, lk = (lane >> 4) * 8;
    f32x4 acc[2][2];
#pragma unroll
    for (int i = 0; i < 2; ++i)
#pragma unroll
        for (int j = 0; j < 2; ++j) acc[i][j] = (f32x4)0.f;
#pragma unroll
    for (int kc = 0; kc < 2; ++kc) {
        const size_t ao = (size_t)(row0 + lr) * 64 + kc * 32 + lk;
        bf16x8 ah0 = ld8(Xhi + ao), ah1 = ld8(Xhi + ao + 16 * 64);
        bf16x8 al0 = ld8(Xlo + ao), al1 = ld8(Xlo + ao + 16 * 64);
#pragma unroll
        for (int cf = 0; cf < 2; ++cf) {
            const size_t bo = (size_t)(cs + cf * 16 + lr) * 64 + kc * 32 + lk;
            bf16x8 bh = ld8(Bhi + bo), bl = ld8(Blo + bo);
            MFMA(acc[0][cf], ah0, bh); MFMA(acc[0][cf], ah0, bl); MFMA(acc[0][cf], al0, bh);
            MFMA(acc[1][cf], ah1, bh); MFMA(acc[1][cf], ah1, bl); MFMA(acc[1][cf], al1, bh);
        }
    }
#pragma unroll
    for (int rf = 0; rf < 2; ++rf)
#pragma unroll
        for (int cf = 0; cf < 2; ++cf)
#pragma unroll
            for (int rg = 0; rg < 4; ++rg) {
                int row = row0 + rf * 16 + (lane >> 4) * 4 + rg;
                int col = cs + cf * 16 + lr;
                float v = tanhf(acc[rf][cf][rg]);
                size_t o = (size_t)row * HDIM + col;
                Hf[o] = v;
                Hh[o] = f2h(v);
            }
}

// ---------------- fused step: fp16 gather, LDS split, GRU GEMM; 2 graphs ----
// 512 threads = 8 waves; block covers 32 node-rows of graph blockIdx.y.
__global__ __launch_bounds__(512, 4) void step_k(const float* __restrict__ Hf0, const float* __restrict__ Hf1,
                                                 const u16* __restrict__ Hh0, const u16* __restrict__ Hh1,
                                                 const int* __restrict__ ro0, const int* __restrict__ ro1,
                                                 const int* __restrict__ ss0, const int* __restrict__ ss1,
                                                 const u16* __restrict__ Wf0h, const u16* __restrict__ Wf0l,
                                                 const u16* __restrict__ Wf1h, const u16* __restrict__ Wf1l,
                                                 const u16* __restrict__ Wh0h, const u16* __restrict__ Wh0l,
                                                 const u16* __restrict__ Wh1h, const u16* __restrict__ Wh1l,
                                                 const float* __restrict__ bi0, const float* __restrict__ bh0,
                                                 const float* __restrict__ bi1, const float* __restrict__ bh1,
                                                 float* __restrict__ Hn0, float* __restrict__ Hn1,
                                                 u16* __restrict__ Hnh0, u16* __restrict__ Hnh1, int Nn) {
    __shared__ u16 agh[32][136];
    __shared__ u16 agl[32][136];
    __shared__ u16 hhh[32][136];
    __shared__ u16 hhl[32][136];
    __shared__ int eidx[1024];
    const int by = blockIdx.y;
    const float* Hf = by ? Hf1 : Hf0;
    const u16* Hh = by ? Hh1 : Hh0;
    const int* row_off = by ? ro1 : ro0;
    const int* ssrc = by ? ss1 : ss0;
    const int tid = threadIdx.x, wave = tid >> 6, lane = tid & 63;
    const int row0 = blockIdx.x * 32;

    // ---- phase 0: stage edge indices into LDS ----
    const int rowEnd = (row0 + 32 < Nn) ? row0 + 32 : Nn;
    const int eLo = row_off[row0];
    const int nE = row_off[rowEnd] - eLo;
    for (int i = tid; i < nE && i < 1024; i += 512) eidx[i] = ssrc[eLo + i];
    __syncthreads();

    // ---- phase 1: gather neighbor-sum of fp16 h (fp32 register accum) ----
#pragma unroll
    for (int q = 0; q < 4; ++q) {
        const int nl = wave * 4 + q;
        const int node = row0 + nl;
        float ax = 0.f, ay = 0.f;
        if (node < Nn) {
            int lo = row_off[node] - eLo, hi = row_off[node + 1] - eLo;
            int hiS = (hi < 1024) ? hi : 1024;
            int i = lo;
            for (; i + 12 <= hiS; i += 12) {
                unsigned u[12];
#pragma unroll
                for (int j = 0; j < 12; ++j)
                    u[j] = *reinterpret_cast<const unsigned*>(Hh + (size_t)eidx[i + j] * HDIM + lane * 2);
#pragma unroll
                for (int j = 0; j < 12; ++j) { float2 v = up2(u[j]); ax += v.x; ay += v.y; }
            }
            for (; i + 4 <= hiS; i += 4) {
                unsigned u[4];
#pragma unroll
                for (int j = 0; j < 4; ++j)
                    u[j] = *reinterpret_cast<const unsigned*>(Hh + (size_t)eidx[i + j] * HDIM + lane * 2);
#pragma unroll
                for (int j = 0; j < 4; ++j) { float2 v = up2(u[j]); ax += v.x; ay += v.y; }
            }
            for (; i < hiS; ++i) {
                float2 v = up2(*reinterpret_cast<const unsigned*>(Hh + (size_t)eidx[i] * HDIM + lane * 2));
                ax += v.x; ay += v.y;
            }
            for (; i < hi; ++i) {   // LDS overflow fallback (degenerate blocks)
                float2 v = up2(*reinterpret_cast<const unsigned*>(Hh + (size_t)ssrc[eLo + i] * HDIM + lane * 2));
                ax += v.x; ay += v.y;
            }
        }
        u16 hx = f2bf(ax), hy = f2bf(ay);
        u16 lx = f2bf(ax - bf2f(hx)), ly = f2bf(ay - bf2f(hy));
        *reinterpret_cast<unsigned*>(&agh[nl][lane * 2]) = (unsigned)hx | ((unsigned)hy << 16);
        *reinterpret_cast<unsigned*>(&agl[nl][lane * 2]) = (unsigned)lx | ((unsigned)ly << 16);
    }

    // ---- phase 1c: stage h rows (fp32, exact), split -> bf16 hi/lo in LDS ----
    {
        const int r = tid >> 4, c0 = (tid & 15) * 8;
        float v[8];
        const float* hp = Hf + (size_t)(row0 + r) * HDIM + c0;
        *reinterpret_cast<float4*>(&v[0]) = *reinterpret_cast<const float4*>(hp);
        *reinterpret_cast<float4*>(&v[4]) = *reinterpret_cast<const float4*>(hp + 4);
        bf16x8 hi, lo;
        split8(v, hi, lo);
        *reinterpret_cast<bf16x8*>(&hhh[r][c0]) = hi;
        *reinterpret_cast<bf16x8*>(&hhl[r][c0]) = lo;
    }
    __syncthreads();

    // ---- phase 2: GEMM + gates; wave owns 16 cols (cs), 32 rows ----
    const u16* Wfhi = by ? Wf1h : Wf0h;  const u16* Wflo = by ? Wf1l : Wf0l;
    const u16* Whhi = by ? Wh1h : Wh0h;  const u16* Whlo = by ? Wh1l : Wh0l;
    const float* bih = by ? bi1 : bi0;   const float* bhh = by ? bh1 : bh0;
    float* Hnf = by ? Hn1 : Hn0;
    u16* Hnh = by ? Hnh1 : Hnh0;
    const int lr = lane & 15, lk = (lane >> 4) * 8, cs = wave * 16;
    f32x4 accI[2][3], accH[2][3];
#pragma unroll
    for (int rf = 0; rf < 2; ++rf)
#pragma unroll
        for (int g = 0; g < 3; ++g) { accI[rf][g] = (f32x4)0.f; accH[rf][g] = (f32x4)0.f; }
#pragma unroll
    for (int kc = 0; kc < 4; ++kc) {
        bf16x8 ga[2], gl[2], ha[2], hl[2];
#pragma unroll
        for (int rf = 0; rf < 2; ++rf) {
            const int rr = rf * 16 + lr, cc = kc * 32 + lk;
            ga[rf] = *reinterpret_cast<const bf16x8*>(&agh[rr][cc]);
            gl[rf] = *reinterpret_cast<const bf16x8*>(&agl[rr][cc]);
            ha[rf] = *reinterpret_cast<const bf16x8*>(&hhh[rr][cc]);
            hl[rf] = *reinterpret_cast<const bf16x8*>(&hhl[rr][cc]);
        }
#pragma unroll
        for (int g = 0; g < 3; ++g) {
            const size_t bo = (size_t)(g * 128 + cs + lr) * HDIM + kc * 32 + lk;
            bf16x8 fh = ld8(Wfhi + bo), fl = ld8(Wflo + bo);
            bf16x8 wh = ld8(Whhi + bo), wl = ld8(Whlo + bo);
#pragma unroll
            for (int rf = 0; rf < 2; ++rf) {
                MFMA(accI[rf][g], ga[rf], fh); MFMA(accI[rf][g], ga[rf], fl); MFMA(accI[rf][g], gl[rf], fh);
                MFMA(accH[rf][g], ha[rf], wh); MFMA(accH[rf][g], ha[rf], wl); MFMA(accH[rf][g], hl[rf], wh);
            }
        }
    }
    const int c = cs + lr;
    const float bir = bih[c], biz = bih[128 + c], bin = bih[256 + c];
    const float bhr = bhh[c], bhz = bhh[128 + c], bhn = bhh[256 + c];
#pragma unroll
    for (int rf = 0; rf < 2; ++rf)
#pragma unroll
        for (int rg = 0; rg < 4; ++rg) {
            const int rl = rf * 16 + (lane >> 4) * 4 + rg;
            const int row = row0 + rl;
            float gir = accI[rf][0][rg] + bir;
            float giz = accI[rf][1][rg] + biz;
            float gin = accI[rf][2][rg] + bin;
            float ghr = accH[rf][0][rg] + bhr;
            float ghz = accH[rf][1][rg] + bhz;
            float ghn = accH[rf][2][rg] + bhn;
            float r = 1.f / (1.f + expf(-(gir + ghr)));
            float z = 1.f / (1.f + expf(-(giz + ghz)));
            float nn = tanhf(gin + r * ghn);
            float hold = bf2f(hhh[rl][c]) + bf2f(hhl[rl][c]);
            float hn = (1.f - z) * nn + z * hold;
            size_t o = (size_t)row * HDIM + c;
            Hnf[o] = hn;
            Hnh[o] = f2h(hn);
        }
}

// ---------------- CSR build (both graphs via blockIdx.y) --------------------
__global__ void zero_int2(int* p0, int* p1, int n) {
    int i = blockIdx.x * 256 + threadIdx.x;
    int* p = blockIdx.y ? p1 : p0;
    if (i < n) p[i] = 0;
}

__global__ void hist_k2(const int* __restrict__ d0, const int* __restrict__ d1,
                        int* __restrict__ c0, int* __restrict__ c1, int E) {
    int e = blockIdx.x * 256 + threadIdx.x;
    const int* dst = blockIdx.y ? d1 : d0;
    int* cnt = blockIdx.y ? c1 : c0;
    if (e < E) atomicAdd(&cnt[dst[e]], 1);
}

// grid.x = 2: block b scans graph b
__global__ __launch_bounds__(1024) void scan_k2(int* __restrict__ c0, int* __restrict__ r0,
                                                int* __restrict__ c1, int* __restrict__ r1, int n) {
    int* cnt_cursor = blockIdx.x ? c1 : c0;
    int* row_off = blockIdx.x ? r1 : r0;
    __shared__ int wsum[16];
    __shared__ int carry_s;
    const int tid = threadIdx.x, lane = tid & 63, wv = tid >> 6;
    if (tid == 0) carry_s = 0;
    __syncthreads();
    for (int base = 0; base < n; base += 1024) {
        int i = base + tid;
        int v = (i < n) ? cnt_cursor[i] : 0;
        int x = v;
#pragma unroll
        for (int off = 1; off < 64; off <<= 1) {
            int t = __shfl_up(x, off);
            if (lane >= off) x += t;
        }
        if (lane == 63) wsum[wv] = x;
        __syncthreads();
        if (wv == 0 && lane < 16) {
            int s = wsum[lane];
#pragma unroll
            for (int off = 1; off < 16; off <<= 1) {
                int t = __shfl_up(s, off);
                if (lane >= off) s += t;
            }
            wsum[lane] = s;
        }
        __syncthreads();
        int wbase = (wv == 0) ? 0 : wsum[wv - 1];
        int carry = carry_s;
        int total = wsum[15];
        int excl = carry + wbase + x - v;
        if (i < n) { row_off[i] = excl; cnt_cursor[i] = excl; }
        __syncthreads();
        if (tid == 0) carry_s = carry + total;
        __syncthreads();
    }
    if (tid == 0) row_off[n] = carry_s;
}

__global__ void scatter_k2(const int* __restrict__ s0, const int* __restrict__ d0,
                           const int* __restrict__ s1, const int* __restrict__ d1,
                           int* __restrict__ c0, int* __restrict__ c1,
                           int* __restrict__ o0, int* __restrict__ o1, int E) {
    int e = blockIdx.x * 256 + threadIdx.x;
    const int* src = blockIdx.y ? s1 : s0;
    const int* dst = blockIdx.y ? d1 : d0;
    int* cursor = blockIdx.y ? c1 : c0;
    int* ssrc = blockIdx.y ? o1 : o0;
    if (e < E) {
        int p = atomicAdd(&cursor[dst[e]], 1);
        ssrc[p] = src[e];
    }
}

// ---------------- mean-pool + relu (both graphs) ----------------------------
__global__ __launch_bounds__(256) void pool_k(const float* __restrict__ H0, const float* __restrict__ H1,
                                              const int* __restrict__ batch,
                                              float* __restrict__ p0, float* __restrict__ p1, int M) {
    const float* Hf = blockIdx.y ? H1 : H0;
    float* pooled = blockIdx.y ? p1 : p0;
    __shared__ int lo_s, hi_s;
    __shared__ float smx[256], smy[256];
    int g = blockIdx.x;
    if (threadIdx.x == 0) {
        int lo = 0, hi = M;
        while (lo < hi) { int mid = (lo + hi) >> 1; if (batch[mid] < g) lo = mid + 1; else hi = mid; }
        lo_s = lo;
        int lo2 = lo, hi2 = M;
        while (lo2 < hi2) { int mid = (lo2 + hi2) >> 1; if (batch[mid] < g + 1) lo2 = mid + 1; else hi2 = mid; }
        hi_s = lo2;
    }
    __syncthreads();
    int lo = lo_s, hi = hi_s;
    int c2 = threadIdx.x & 63, quarter = threadIdx.x >> 6;
    float ax = 0.f, ay = 0.f;
    for (int i = lo + quarter; i < hi; i += 4) {
        float2 v = *reinterpret_cast<const float2*>(Hf + (size_t)i * HDIM + c2 * 2);
        ax += v.x; ay += v.y;
    }
    smx[threadIdx.x] = ax; smy[threadIdx.x] = ay;
    __syncthreads();
    if (quarter == 0) {
        float sx = smx[c2] + smx[c2 + 64] + smx[c2 + 128] + smx[c2 + 192];
        float sy = smy[c2] + smy[c2 + 64] + smy[c2 + 128] + smy[c2 + 192];
        float cnt = (float)(hi - lo); if (cnt < 1.f) cnt = 1.f;
        pooled[g * HDIM + c2 * 2]     = fmaxf(sx / cnt, 0.f);
        pooled[g * HDIM + c2 * 2 + 1] = fmaxf(sy / cnt, 0.f);
    }
}

// ---------------- prediction head -------------------------------------------
__global__ void pred_kernel(const float* __restrict__ pa, const float* __restrict__ pv,
                            const float* __restrict__ pW, const float* __restrict__ pb,
                            float* __restrict__ out) {
    int g = blockIdx.x, lane = threadIdx.x; // 64 threads
    float s = pa[g * HDIM + lane] * pW[lane]
            + pa[g * HDIM + 64 + lane] * pW[64 + lane]
            + pv[g * HDIM + lane] * pW[HDIM + lane]
            + pv[g * HDIM + 64 + lane] * pW[192 + lane];
    for (int off = 32; off; off >>= 1) s += __shfl_down(s, off);
    if (lane == 0) out[g] = s + pb[0];
}

extern "C" void kernel_launch(void* const* d_in, const int* in_sizes, int n_in,
                              void* d_out, int out_size, void* d_ws, size_t ws_size,
                              hipStream_t stream) {
    const float* atom_x   = (const float*)d_in[0];
    const float* voro_x   = (const float*)d_in[1];
    const int*   atom_ei  = (const int*)d_in[2];
    const int*   voro_ei  = (const int*)d_in[3];
    const int*   batch    = (const int*)d_in[4];
    const float* W_at_in  = (const float*)d_in[5];
    const float* W_vo_in  = (const float*)d_in[6];
    const float* atom_W   = (const float*)d_in[7];
    const float* voro_W   = (const float*)d_in[8];
    const float* atom_Wih = (const float*)d_in[9];
    const float* atom_Whh = (const float*)d_in[10];
    const float* atom_bih = (const float*)d_in[11];
    const float* atom_bhh = (const float*)d_in[12];
    const float* voro_Wih = (const float*)d_in[13];
    const float* voro_Whh = (const float*)d_in[14];
    const float* voro_bih = (const float*)d_in[15];
    const float* voro_bhh = (const float*)d_in[16];
    const float* pred_W   = (const float*)d_in[17];
    const float* pred_b   = (const float*)d_in[18];
    float* out = (float*)d_out;

    const int Nn = in_sizes[4];
    const int Ee = in_sizes[2] / 2;
    const int Gg = out_size;
    const int Npad = (Nn + 31) & ~31;

    char* base = (char*)d_ws;
    size_t off = 0;
    auto alloc = [&](size_t bytes) -> char* {
        char* p = base + off;
        off = (off + bytes + 255) & ~(size_t)255;
        return p;
    };

    float *Hf[2], *Hnf[2];
    u16 *HhA[2], *HhB[2];
    u16 *Xhi[2], *Xlo[2];
    u16 *WfHi[2], *WfLo[2], *WhHi[2], *WhLo[2], *WnHi[2], *WnLo[2];
    int *row_off[2], *cursor[2], *ssrc[2];
    for (int t = 0; t < 2; ++t) {
        Hf[t]  = (float*)alloc((size_t)Npad * HDIM * 4);
        Hnf[t] = (float*)alloc((size_t)Npad * HDIM * 4);
        HhA[t] = (u16*)alloc((size_t)Npad * HDIM * 2);
        HhB[t] = (u16*)alloc((size_t)Npad * HDIM * 2);
        Xhi[t] = (u16*)Hnf[t];                 // X aliases Hnf (dead after embed)
        Xlo[t] = Xhi[t] + (size_t)Npad * 64;
        WfHi[t] = (u16*)alloc(4 * 49152 * 2); WfLo[t] = (u16*)alloc(4 * 49152 * 2);
        WhHi[t] = (u16*)alloc(384 * 128 * 2); WhLo[t] = (u16*)alloc(384 * 128 * 2);
        WnHi[t] = (u16*)alloc(128 * 64 * 2);  WnLo[t] = (u16*)alloc(128 * 64 * 2);
        row_off[t] = (int*)alloc((size_t)(Nn + 1) * 4);
        cursor[t]  = (int*)alloc((size_t)Nn * 4);
        ssrc[t]    = (int*)alloc((size_t)Ee * 4);
    }
    float* pooledA = (float*)alloc((size_t)Gg * HDIM * 4);
    float* pooledV = (float*)alloc((size_t)Gg * HDIM * 4);

    const float* Wst[2] = {atom_W, voro_W};
    const float* Wih[2] = {atom_Wih, voro_Wih};
    const float* Whh[2] = {atom_Whh, voro_Whh};
    const float* Win[2] = {W_at_in, W_vo_in};

    // weight prep
    for (int t = 0; t < 2; ++t) {
        prep_wfull<<<dim3(192, 4), 256, 0, stream>>>(Wst[t], Wih[t], WfHi[t], WfLo[t]);
        prep_split<<<192, 256, 0, stream>>>(Whh[t], WhHi[t], WhLo[t], 384 * 128);
        prep_win<<<32, 256, 0, stream>>>(Win[t], WnHi[t], WnLo[t]);
    }

    const int eb  = (Ee + 255) / 256;
    const int nb  = (Nn + 255) / 256;
    const int gbs = Npad / 32;

    split_x2<<<dim3((Npad * 64 + 255) / 256, 2), 256, 0, stream>>>(
        atom_x, voro_x, Xhi[0], Xlo[0], Xhi[1], Xlo[1], Nn * 64, Npad * 64);
    embed_k<<<dim3(gbs, 2), 256, 0, stream>>>(Xhi[0], Xlo[0], Xhi[1], Xlo[1],
                                              WnHi[0], WnLo[0], WnHi[1], WnLo[1],
                                              Hf[0], Hf[1], HhA[0], HhA[1]);

    zero_int2<<<dim3(nb, 2), 256, 0, stream>>>(cursor[0], cursor[1], Nn);
    hist_k2<<<dim3(eb, 2), 256, 0, stream>>>(atom_ei + Ee, voro_ei + Ee, cursor[0], cursor[1], Ee);
    scan_k2<<<2, 1024, 0, stream>>>(cursor[0], row_off[0], cursor[1], row_off[1], Nn);
    scatter_k2<<<dim3(eb, 2), 256, 0, stream>>>(atom_ei, atom_ei + Ee, voro_ei, voro_ei + Ee,
                                                cursor[0], cursor[1], ssrc[0], ssrc[1], Ee);

    float *hA0 = Hf[0], *hB0 = Hnf[0], *hA1 = Hf[1], *hB1 = Hnf[1];
    u16 *gA0 = HhA[0], *gB0 = HhB[0], *gA1 = HhA[1], *gB1 = HhB[1];
    for (int s = 0; s < 4; ++s) {
        step_k<<<dim3(gbs, 2), 512, 0, stream>>>(
            hA0, hA1, gA0, gA1, row_off[0], row_off[1], ssrc[0], ssrc[1],
            WfHi[0] + (size_t)s * 49152, WfLo[0] + (size_t)s * 49152,
            WfHi[1] + (size_t)s * 49152, WfLo[1] + (size_t)s * 49152,
            WhHi[0], WhLo[0], WhHi[1], WhLo[1],
            atom_bih, atom_bhh, voro_bih, voro_bhh,
            hB0, hB1, gB0, gB1, Nn);
        float* tp;
        tp = hA0; hA0 = hB0; hB0 = tp;
        tp = hA1; hA1 = hB1; hB1 = tp;
        u16* up;
        up = gA0; gA0 = gB0; gB0 = up;
        up = gA1; gA1 = gB1; gB1 = up;
    }
    pool_k<<<dim3(Gg, 2), 256, 0, stream>>>(hA0, hA1, batch, pooledA, pooledV, Nn);
    pred_kernel<<<Gg, 64, 0, stream>>>(pooledA, pooledV, pred_W, pred_b, out);
}